// Round 1
// baseline (477.208 us; speedup 1.0000x reference)
//
#include <hip/hip_runtime.h>
#include <math.h>

#define N 1024
#define HID 512
#define NH 16
#define DH 32
#define NEDGE 1025

// ---------------- centrality: h = x + in_deg_emb[ind] + out_deg_emb[outd] ----
__global__ void centrality_k(const float* __restrict__ x, const int* __restrict__ ind,
                             const int* __restrict__ outd, const float* __restrict__ ide,
                             const float* __restrict__ ode, float* __restrict__ h) {
  int i = blockIdx.x; int t = threadIdx.x;              // 128 threads, float4 each
  int a = ind[i], b = outd[i];
  float4 xv = ((const float4*)(x + (size_t)i*HID))[t];
  float4 av = ((const float4*)(ide + (size_t)a*HID))[t];
  float4 bv = ((const float4*)(ode + (size_t)b*HID))[t];
  float4 r;
  r.x = xv.x+av.x+bv.x; r.y = xv.y+av.y+bv.y;
  r.z = xv.z+av.z+bv.z; r.w = xv.w+av.w+bv.w;
  ((float4*)(h + (size_t)i*HID))[t] = r;
}

// ---------------- edge table: T[e][k][h] = sum_d edge_emb[e][d]*pos_w[k][d][h]
__global__ void edge_table_k(const float* __restrict__ ee, const float* __restrict__ epe,
                             float* __restrict__ T) {
  int t = blockIdx.x*256 + threadIdx.x;
  if (t >= NEDGE*64) return;
  int e = t >> 6; int r = t & 63; int k = r >> 4; int hh = r & 15;
  const float* erow = ee + (size_t)e*32;
  const float* w = epe + k*512 + hh;                     // pos_w[k][d][hh] = epe[k*512 + d*16 + hh]
  float acc = 0.f;
  #pragma unroll
  for (int d = 0; d < 32; ++d) acc += erow[d] * w[d*16];
  T[t] = acc;
}

// ---------------- bias: S[h][i][j] = spatial_emb[sp][h] + (sum_k T[e_k][k][h])/plen
__global__ void bias_k(const int* __restrict__ sp, const int* __restrict__ ei,
                       const float* __restrict__ se, const float* __restrict__ T,
                       float* __restrict__ S) {
  int p = blockIdx.x*256 + threadIdx.x;                  // pair index i*N+j
  int4 e = ((const int4*)ei)[p];
  int cnt = (e.x!=0)+(e.y!=0)+(e.z!=0)+(e.w!=0);
  float inv = 1.0f / (float)(cnt > 0 ? cnt : 1);
  const float4* f0 = (const float4*)(T + (size_t)e.x*64);
  const float4* f1 = (const float4*)(T + (size_t)e.y*64 + 16);
  const float4* f2 = (const float4*)(T + (size_t)e.z*64 + 32);
  const float4* f3 = (const float4*)(T + (size_t)e.w*64 + 48);
  float acc[16];
  #pragma unroll
  for (int u = 0; u < 4; ++u) {
    float4 a = f0[u], b = f1[u], c = f2[u], d = f3[u];
    acc[u*4+0] = a.x+b.x+c.x+d.x;
    acc[u*4+1] = a.y+b.y+c.y+d.y;
    acc[u*4+2] = a.z+b.z+c.z+d.z;
    acc[u*4+3] = a.w+b.w+c.w+d.w;
  }
  int s = sp[p];
  const float* srow = se + (size_t)s*16;
  #pragma unroll
  for (int hh = 0; hh < 16; ++hh)
    S[(size_t)hh*(N*(size_t)N) + p] = srow[hh] + acc[hh]*inv;
}

// ---------------- generic GEMM: C[1024][Nc] = A[1024][K] @ W[K][Nc] + bias ----
template<bool RELU>
__global__ void gemm_k(const float* __restrict__ A, const float* __restrict__ W,
                       const float* __restrict__ bias, float* __restrict__ C,
                       int K, int Nc) {
  __shared__ float As[8*1024];
  int tid = threadIdx.x;
  int c = blockIdx.x*256 + tid;
  int i0 = blockIdx.y*8;
  const float* Ablk = A + (size_t)i0*K;
  for (int idx = tid; idx < 8*K; idx += 256) As[idx] = Ablk[idx];
  __syncthreads();
  float acc[8] = {0,0,0,0,0,0,0,0};
  for (int k = 0; k < K; k += 4) {
    float w0 = W[(size_t)(k+0)*Nc + c];
    float w1 = W[(size_t)(k+1)*Nc + c];
    float w2 = W[(size_t)(k+2)*Nc + c];
    float w3 = W[(size_t)(k+3)*Nc + c];
    #pragma unroll
    for (int r = 0; r < 8; ++r) {
      float4 a = *(const float4*)&As[r*K + k];
      acc[r] += a.x*w0 + a.y*w1 + a.z*w2 + a.w*w3;
    }
  }
  float bb = bias[c];
  #pragma unroll
  for (int r = 0; r < 8; ++r) {
    float v = acc[r] + bb;
    if (RELU) v = fmaxf(v, 0.f);
    C[(size_t)(i0+r)*Nc + c] = v;
  }
}

// ---------------- scores: S[h][i][j] += sqrt(32) * q_i . k_j  (head h) -------
__global__ void scores_k(const float* __restrict__ q, const float* __restrict__ kmat,
                         float* __restrict__ S) {
  __shared__ float qs[32][33];
  __shared__ float ks[64][33];
  int tid = threadIdx.x;
  int h = blockIdx.z;
  int i0 = blockIdx.y*32;
  int j0 = blockIdx.x*64;
  {
    int r = tid >> 3; int c = (tid & 7) * 4;
    float4 v = *(const float4*)(q + (size_t)(i0+r)*HID + h*DH + c);
    qs[r][c]=v.x; qs[r][c+1]=v.y; qs[r][c+2]=v.z; qs[r][c+3]=v.w;
  }
  {
    int r = tid >> 2; int c = (tid & 3) * 8;
    const float* src = kmat + (size_t)(j0+r)*HID + h*DH + c;
    float4 v = *(const float4*)src;
    float4 v2 = *(const float4*)(src+4);
    ks[r][c]=v.x; ks[r][c+1]=v.y; ks[r][c+2]=v.z; ks[r][c+3]=v.w;
    ks[r][c+4]=v2.x; ks[r][c+5]=v2.y; ks[r][c+6]=v2.z; ks[r][c+7]=v2.w;
  }
  __syncthreads();
  int j = tid & 63;
  int ib = tid >> 6;                                     // 0..3, wave-uniform
  float acc[8] = {0,0,0,0,0,0,0,0};
  for (int d = 0; d < DH; ++d) {
    float kv = ks[j][d];
    #pragma unroll
    for (int r = 0; r < 8; ++r) acc[r] += qs[ib*8+r][d]*kv;
  }
  const float sc = 5.656854249492380195f;                // sqrt(DH)
  #pragma unroll
  for (int r = 0; r < 8; ++r) {
    size_t idx = ((size_t)h*N + (i0 + ib*8 + r))*N + j0 + j;
    S[idx] += sc*acc[r];
  }
}

// ---------------- softmax in-place over last dim of S[h][i][:] ---------------
__global__ void softmax_k(float* __restrict__ S) {
  size_t row = blockIdx.x;                               // h*N+i, 16384 rows
  float* p = S + row*N;
  int tid = threadIdx.x;                                 // 256
  float4 v = ((float4*)p)[tid];
  float m = fmaxf(fmaxf(v.x,v.y), fmaxf(v.z,v.w));
  for (int o = 32; o; o >>= 1) m = fmaxf(m, __shfl_xor(m, o));
  __shared__ float sm[4];
  __shared__ float ss[4];
  if ((tid & 63) == 0) sm[tid>>6] = m;
  __syncthreads();
  m = fmaxf(fmaxf(sm[0],sm[1]), fmaxf(sm[2],sm[3]));
  float e0 = __expf(v.x-m), e1 = __expf(v.y-m), e2 = __expf(v.z-m), e3 = __expf(v.w-m);
  float s = e0+e1+e2+e3;
  for (int o = 32; o; o >>= 1) s += __shfl_xor(s, o);
  if ((tid & 63) == 0) ss[tid>>6] = s;
  __syncthreads();
  s = ss[0]+ss[1]+ss[2]+ss[3];
  float inv = 1.f/s;
  ((float4*)p)[tid] = make_float4(e0*inv, e1*inv, e2*inv, e3*inv);
}

// ---------------- PV: o[i][h*32+d] = sum_j attn[h][i][j] * v[j][h*32+d] ------
__global__ void pv_k(const float* __restrict__ Smat, const float* __restrict__ vmat,
                     float* __restrict__ o) {
  __shared__ float as[32][64];
  __shared__ float vs[64][33];
  int tid = threadIdx.x;
  int h = blockIdx.y;
  int i0 = blockIdx.x*32;
  int d = tid & 31;
  int ig = tid >> 5;                                     // 0..7
  float acc[4] = {0,0,0,0};
  for (int j0 = 0; j0 < N; j0 += 64) {
    __syncthreads();
    {
      int r = tid >> 3; int c = (tid & 7)*8;
      const float* src = Smat + ((size_t)h*N + i0 + r)*N + j0 + c;
      float4 a0 = *(const float4*)src;
      float4 a1 = *(const float4*)(src+4);
      as[r][c]=a0.x; as[r][c+1]=a0.y; as[r][c+2]=a0.z; as[r][c+3]=a0.w;
      as[r][c+4]=a1.x; as[r][c+5]=a1.y; as[r][c+6]=a1.z; as[r][c+7]=a1.w;
    }
    {
      int r = tid >> 2; int c = (tid & 3)*8;
      const float* src = vmat + (size_t)(j0+r)*HID + h*DH + c;
      float4 a0 = *(const float4*)src;
      float4 a1 = *(const float4*)(src+4);
      vs[r][c]=a0.x; vs[r][c+1]=a0.y; vs[r][c+2]=a0.z; vs[r][c+3]=a0.w;
      vs[r][c+4]=a1.x; vs[r][c+5]=a1.y; vs[r][c+6]=a1.z; vs[r][c+7]=a1.w;
    }
    __syncthreads();
    for (int jj = 0; jj < 64; ++jj) {
      float vv = vs[jj][d];
      #pragma unroll
      for (int r = 0; r < 4; ++r) acc[r] += as[ig*4+r][jj]*vv;
    }
  }
  #pragma unroll
  for (int r = 0; r < 4; ++r)
    o[(size_t)(i0+ig*4+r)*HID + h*DH + d] = acc[r];
}

// ---------------- residual + layernorm -------------------------------------
__global__ void add_ln_k(const float* __restrict__ a, const float* __restrict__ b,
                         const float* __restrict__ g, const float* __restrict__ be,
                         float* __restrict__ out) {
  int i = blockIdx.x; int tid = threadIdx.x;             // 128 threads, float4
  float4 av = ((const float4*)(a + (size_t)i*HID))[tid];
  float4 bv = ((const float4*)(b + (size_t)i*HID))[tid];
  float4 v;
  v.x = av.x+bv.x; v.y = av.y+bv.y; v.z = av.z+bv.z; v.w = av.w+bv.w;
  float s = v.x+v.y+v.z+v.w;
  float s2 = v.x*v.x+v.y*v.y+v.z*v.z+v.w*v.w;
  for (int o = 32; o; o >>= 1) { s += __shfl_xor(s, o); s2 += __shfl_xor(s2, o); }
  __shared__ float sa[2], sb[2];
  if ((tid & 63) == 0) { sa[tid>>6] = s; sb[tid>>6] = s2; }
  __syncthreads();
  s = sa[0]+sa[1]; s2 = sb[0]+sb[1];
  float mean = s*(1.f/HID);
  float var = s2*(1.f/HID) - mean*mean;
  float rinv = rsqrtf(var + 1e-5f);
  float4 gv = ((const float4*)g)[tid];
  float4 bev = ((const float4*)be)[tid];
  float4 r;
  r.x = (v.x-mean)*rinv*gv.x + bev.x;
  r.y = (v.y-mean)*rinv*gv.y + bev.y;
  r.z = (v.z-mean)*rinv*gv.z + bev.z;
  r.w = (v.w-mean)*rinv*gv.w + bev.w;
  ((float4*)(out + (size_t)i*HID))[tid] = r;
}

extern "C" void kernel_launch(void* const* d_in, const int* in_sizes, int n_in,
                              void* d_out, int out_size, void* d_ws, size_t ws_size,
                              hipStream_t stream) {
  const float* x            = (const float*)d_in[0];
  const int*   spatial_pos  = (const int*)d_in[1];
  const int*   edge_input   = (const int*)d_in[2];
  const int*   in_degree    = (const int*)d_in[3];
  const int*   out_degree   = (const int*)d_in[4];
  const float* spatial_emb  = (const float*)d_in[5];
  const float* edge_emb     = (const float*)d_in[6];
  const float* edge_pos_emb = (const float*)d_in[7];
  const float* in_deg_emb   = (const float*)d_in[8];
  const float* out_deg_emb  = (const float*)d_in[9];
  const float* Wq = (const float*)d_in[10]; const float* bq = (const float*)d_in[11];
  const float* Wk = (const float*)d_in[12]; const float* bk = (const float*)d_in[13];
  const float* Wv = (const float*)d_in[14]; const float* bv = (const float*)d_in[15];
  const float* Wo = (const float*)d_in[16]; const float* bo = (const float*)d_in[17];
  const float* W1 = (const float*)d_in[18]; const float* b1 = (const float*)d_in[19];
  const float* W2 = (const float*)d_in[20]; const float* b2 = (const float*)d_in[21];
  const float* g1 = (const float*)d_in[22]; const float* be1 = (const float*)d_in[23];
  const float* g2 = (const float*)d_in[24]; const float* be2 = (const float*)d_in[25];

  float* ws = (float*)d_ws;
  float* S    = ws;                       // 16 M floats (64 MB)
  float* h    = S + (size_t)16*1024*1024;
  float* q    = h + 524288;
  float* kbuf = q + 524288;
  float* vbuf = kbuf + 524288;
  float* obuf = vbuf + 524288;
  float* mid  = obuf + 524288;            // 1 M floats
  float* T    = mid + 1048576;            // 65600 floats
  float* out  = (float*)d_out;

  centrality_k<<<N, 128, 0, stream>>>(x, in_degree, out_degree, in_deg_emb, out_deg_emb, h);
  edge_table_k<<<(NEDGE*64 + 255)/256, 256, 0, stream>>>(edge_emb, edge_pos_emb, T);
  bias_k<<<(N*N)/256, 256, 0, stream>>>(spatial_pos, edge_input, spatial_emb, T, S);

  gemm_k<false><<<dim3(2,128), 256, 0, stream>>>(h, Wq, bq, q,    512, 512);
  gemm_k<false><<<dim3(2,128), 256, 0, stream>>>(h, Wk, bk, kbuf, 512, 512);
  gemm_k<false><<<dim3(2,128), 256, 0, stream>>>(h, Wv, bv, vbuf, 512, 512);

  scores_k<<<dim3(N/64, N/32, NH), 256, 0, stream>>>(q, kbuf, S);
  softmax_k<<<NH*N, 256, 0, stream>>>(S);
  pv_k<<<dim3(N/32, NH), 256, 0, stream>>>(S, vbuf, obuf);

  gemm_k<false><<<dim3(2,128), 256, 0, stream>>>(obuf, Wo, bo, q, 512, 512);   // y -> q
  add_ln_k<<<N, 128, 0, stream>>>(h, q, g1, be1, kbuf);                        // h1 -> kbuf
  gemm_k<true ><<<dim3(4,128), 256, 0, stream>>>(kbuf, W1, b1, mid, 512, 1024);
  gemm_k<false><<<dim3(2,128), 256, 0, stream>>>(mid, W2, b2, vbuf, 1024, 512); // f -> vbuf
  add_ln_k<<<N, 128, 0, stream>>>(kbuf, vbuf, g2, be2, out);
}

// Round 2
// 217.143 us; speedup vs baseline: 2.1977x; 2.1977x over previous
//
#include <hip/hip_runtime.h>
#include <math.h>

#define N 1024
#define HID 512
#define NH 16
#define DH 32
#define NEDGE 1025

typedef __attribute__((ext_vector_type(8))) __bf16 bf16x8;
typedef __attribute__((ext_vector_type(4))) short short4v;
typedef __attribute__((ext_vector_type(4))) float f32x4;

__device__ inline short f2bf(float f) {
  unsigned u = __builtin_bit_cast(unsigned, f);
  u += 0x7fffu + ((u >> 16) & 1u);
  return (short)(u >> 16);
}
__device__ inline float bf2f(short s) {
  unsigned u = ((unsigned)(unsigned short)s) << 16;
  return __builtin_bit_cast(float, u);
}

// ---------------- centrality: h = x + ide[ind] + ode[outd]; also bf16 copy ---
__global__ void centrality_k(const float* __restrict__ x, const int* __restrict__ ind,
                             const int* __restrict__ outd, const float* __restrict__ ide,
                             const float* __restrict__ ode, float* __restrict__ h,
                             short* __restrict__ hb) {
  int i = blockIdx.x; int t = threadIdx.x;              // 128 threads, float4 each
  int a = ind[i], b = outd[i];
  float4 xv = ((const float4*)(x + (size_t)i*HID))[t];
  float4 av = ((const float4*)(ide + (size_t)a*HID))[t];
  float4 bv = ((const float4*)(ode + (size_t)b*HID))[t];
  float4 r;
  r.x = xv.x+av.x+bv.x; r.y = xv.y+av.y+bv.y;
  r.z = xv.z+av.z+bv.z; r.w = xv.w+av.w+bv.w;
  ((float4*)(h + (size_t)i*HID))[t] = r;
  short4v o = { f2bf(r.x), f2bf(r.y), f2bf(r.z), f2bf(r.w) };
  ((short4v*)(hb + (size_t)i*HID))[t] = o;
}

// ---------------- edge table: T[e][k][h] = sum_d edge_emb[e][d]*pos_w[k][d][h]
__global__ void edge_table_k(const float* __restrict__ ee, const float* __restrict__ epe,
                             float* __restrict__ T) {
  int t = blockIdx.x*256 + threadIdx.x;
  if (t >= NEDGE*64) return;
  int e = t >> 6; int r = t & 63; int k = r >> 4; int hh = r & 15;
  const float* erow = ee + (size_t)e*32;
  const float* w = epe + k*512 + hh;
  float acc = 0.f;
  #pragma unroll
  for (int d = 0; d < 32; ++d) acc += erow[d] * w[d*16];
  T[t] = acc;
}

// ---------------- bias: S[h][i][j] = spatial + avg_k T[e_k][k][h] ------------
__global__ void bias_k(const int* __restrict__ sp, const int* __restrict__ ei,
                       const float* __restrict__ se, const float* __restrict__ T,
                       float* __restrict__ S) {
  int p = blockIdx.x*256 + threadIdx.x;
  int4 e = ((const int4*)ei)[p];
  int cnt = (e.x!=0)+(e.y!=0)+(e.z!=0)+(e.w!=0);
  float inv = 1.0f / (float)(cnt > 0 ? cnt : 1);
  const float4* f0 = (const float4*)(T + (size_t)e.x*64);
  const float4* f1 = (const float4*)(T + (size_t)e.y*64 + 16);
  const float4* f2 = (const float4*)(T + (size_t)e.z*64 + 32);
  const float4* f3 = (const float4*)(T + (size_t)e.w*64 + 48);
  float acc[16];
  #pragma unroll
  for (int u = 0; u < 4; ++u) {
    float4 a = f0[u], b = f1[u], c = f2[u], d = f3[u];
    acc[u*4+0] = a.x+b.x+c.x+d.x;
    acc[u*4+1] = a.y+b.y+c.y+d.y;
    acc[u*4+2] = a.z+b.z+c.z+d.z;
    acc[u*4+3] = a.w+b.w+c.w+d.w;
  }
  int s = sp[p];
  const float* srow = se + (size_t)s*16;
  #pragma unroll
  for (int hh = 0; hh < 16; ++hh)
    S[(size_t)hh*(N*(size_t)N) + p] = srow[hh] + acc[hh]*inv;
}

// ---------------- weight transpose + bf16: Wt[n][k] = bf16(Win[k][n]) --------
__global__ void wtr_k(const float* __restrict__ Win, short* __restrict__ Wt, int K, int Nc) {
  __shared__ float tile[32][33];
  int n0 = blockIdx.x*32, k0 = blockIdx.y*32;
  int tid = threadIdx.x;
  int r = tid >> 3, c = (tid & 7) * 4;
  float4 v = *(const float4*)(Win + (size_t)(k0+r)*Nc + n0 + c);
  tile[r][c]=v.x; tile[r][c+1]=v.y; tile[r][c+2]=v.z; tile[r][c+3]=v.w;
  __syncthreads();
  short4v o = { f2bf(tile[c+0][r]), f2bf(tile[c+1][r]), f2bf(tile[c+2][r]), f2bf(tile[c+3][r]) };
  *(short4v*)(Wt + (size_t)(n0+r)*K + k0 + c) = o;
}

// ---------------- MFMA GEMM: C[M][Nc] = A[M][K](bf16) @ Bt[Nc][K]^T + bias ---
// BM=64, BK=64; BN template (32 or 64). 256 threads.
template<int BN, int RELU, int F32OUT, int BF16OUT>
__launch_bounds__(256)
__global__ void gemm_mfma(const short* __restrict__ A, const short* __restrict__ Bt,
                          const float* __restrict__ bias, float scale,
                          float* __restrict__ Cf, short* __restrict__ Cb,
                          int K, int Nc) {
  __shared__ short As[64*64];
  __shared__ short Bs[BN*64];
  constexpr int WN = BN/32;        // wave-col groups: 2 (BN=64) or 1 (BN=32)
  constexpr int WM = 4/WN;         // wave-row groups
  constexpr int MI = 64/(WM*16);   // m-frags per wave: 2 or 1
  int tid = threadIdx.x;
  int w = tid >> 6, l = tid & 63;
  int lr = l & 15, kg = l >> 4;
  int wn = (WN == 1) ? 0 : (w & 1);
  int wm = (WN == 1) ? w : (w >> 1);
  int i0 = blockIdx.y*64, n0 = blockIdx.x*BN;
  int srow = tid >> 3, sslot = tid & 7;
  f32x4 acc[MI][2];
  #pragma unroll
  for (int mi=0; mi<MI; ++mi)
    #pragma unroll
    for (int ni=0; ni<2; ++ni) acc[mi][ni] = (f32x4){0.f,0.f,0.f,0.f};
  const short* Ag = A + (size_t)i0*K;
  const short* Bg = Bt + (size_t)n0*K;
  for (int k0 = 0; k0 < K; k0 += 64) {
    bf16x8 va0 = *(const bf16x8*)(Ag + (size_t)srow*K + k0 + sslot*8);
    bf16x8 va1 = *(const bf16x8*)(Ag + (size_t)(srow+32)*K + k0 + sslot*8);
    bf16x8 vb0 = *(const bf16x8*)(Bg + (size_t)srow*K + k0 + sslot*8);
    bf16x8 vb1;
    if (BN == 64) vb1 = *(const bf16x8*)(Bg + (size_t)(srow+32)*K + k0 + sslot*8);
    __syncthreads();
    *(bf16x8*)((char*)As + srow*128 + ((sslot ^ (srow&7))<<4)) = va0;
    *(bf16x8*)((char*)As + (srow+32)*128 + ((sslot ^ (srow&7))<<4)) = va1;
    *(bf16x8*)((char*)Bs + srow*128 + ((sslot ^ (srow&7))<<4)) = vb0;
    if (BN == 64)
      *(bf16x8*)((char*)Bs + (srow+32)*128 + ((sslot ^ (srow&7))<<4)) = vb1;
    __syncthreads();
    #pragma unroll
    for (int ks = 0; ks < 2; ++ks) {
      bf16x8 fa[MI], fb[2];
      #pragma unroll
      for (int mi=0; mi<MI; ++mi) {
        int r = wm*(64/WM) + mi*16 + lr;
        fa[mi] = *(const bf16x8*)((const char*)As + r*128 + (((ks*4+kg) ^ (r&7))<<4));
      }
      #pragma unroll
      for (int ni=0; ni<2; ++ni) {
        int r = wn*32 + ni*16 + lr;
        fb[ni] = *(const bf16x8*)((const char*)Bs + r*128 + (((ks*4+kg) ^ (r&7))<<4));
      }
      #pragma unroll
      for (int mi=0; mi<MI; ++mi)
        #pragma unroll
        for (int ni=0; ni<2; ++ni)
          acc[mi][ni] = __builtin_amdgcn_mfma_f32_16x16x32_bf16(fa[mi], fb[ni], acc[mi][ni], 0, 0, 0);
    }
  }
  #pragma unroll
  for (int mi=0; mi<MI; ++mi) {
    #pragma unroll
    for (int ni=0; ni<2; ++ni) {
      int c = n0 + wn*32 + ni*16 + lr;
      float bb = bias[c];
      #pragma unroll
      for (int r=0; r<4; ++r) {
        int rr = i0 + wm*(64/WM) + mi*16 + kg*4 + r;
        float v = (acc[mi][ni][r] + bb) * scale;
        if (RELU) v = fmaxf(v, 0.f);
        if (F32OUT) Cf[(size_t)rr*Nc + c] = v;
        if (BF16OUT) Cb[(size_t)rr*Nc + c] = f2bf(v);
      }
    }
  }
}

// ---------------- scores: S[h] = q_h k_h^T + S[h] (bias as MFMA C-in) --------
__launch_bounds__(256)
__global__ void scores_mfma(const short* __restrict__ qb, const short* __restrict__ kb,
                            float* __restrict__ S) {
  __shared__ short Qs[64*32];
  __shared__ short Ks[64*32];
  int tid = threadIdx.x;
  int w = tid >> 6, l = tid & 63, lr = l & 15, kg = l >> 4;
  int wm = w >> 1, wn = w & 1;
  int j0 = blockIdx.x*64, i0 = blockIdx.y*64, hh = blockIdx.z;
  int srow = tid >> 2, sslot = tid & 3;
  bf16x8 vq = *(const bf16x8*)(qb + (size_t)(i0+srow)*HID + hh*DH + sslot*8);
  bf16x8 vk = *(const bf16x8*)(kb + (size_t)(j0+srow)*HID + hh*DH + sslot*8);
  *(bf16x8*)((char*)Qs + srow*64 + ((sslot ^ ((srow>>1)&3))<<4)) = vq;
  *(bf16x8*)((char*)Ks + srow*64 + ((sslot ^ ((srow>>1)&3))<<4)) = vk;
  f32x4 acc[2][2];
  #pragma unroll
  for (int mi=0; mi<2; ++mi)
    #pragma unroll
    for (int ni=0; ni<2; ++ni)
      #pragma unroll
      for (int r=0; r<4; ++r)
        acc[mi][ni][r] = S[((size_t)hh*N + i0 + wm*32 + mi*16 + kg*4 + r)*N + j0 + wn*32 + ni*16 + lr];
  __syncthreads();
  bf16x8 fq[2], fk[2];
  #pragma unroll
  for (int mi=0; mi<2; ++mi) {
    int r = wm*32 + mi*16 + lr;
    fq[mi] = *(const bf16x8*)((const char*)Qs + r*64 + ((kg ^ ((r>>1)&3))<<4));
  }
  #pragma unroll
  for (int ni=0; ni<2; ++ni) {
    int r = wn*32 + ni*16 + lr;
    fk[ni] = *(const bf16x8*)((const char*)Ks + r*64 + ((kg ^ ((r>>1)&3))<<4));
  }
  #pragma unroll
  for (int mi=0; mi<2; ++mi)
    #pragma unroll
    for (int ni=0; ni<2; ++ni)
      acc[mi][ni] = __builtin_amdgcn_mfma_f32_16x16x32_bf16(fq[mi], fk[ni], acc[mi][ni], 0, 0, 0);
  #pragma unroll
  for (int mi=0; mi<2; ++mi)
    #pragma unroll
    for (int ni=0; ni<2; ++ni)
      #pragma unroll
      for (int r=0; r<4; ++r)
        S[((size_t)hh*N + i0 + wm*32 + mi*16 + kg*4 + r)*N + j0 + wn*32 + ni*16 + lr] = acc[mi][ni][r];
}

// ---------------- softmax in-place over last dim of S[h][i][:] ---------------
__global__ void softmax_k(float* __restrict__ S) {
  size_t row = blockIdx.x;
  float* p = S + row*N;
  int tid = threadIdx.x;
  float4 v = ((float4*)p)[tid];
  float m = fmaxf(fmaxf(v.x,v.y), fmaxf(v.z,v.w));
  for (int o = 32; o; o >>= 1) m = fmaxf(m, __shfl_xor(m, o));
  __shared__ float sm[4];
  __shared__ float ss[4];
  if ((tid & 63) == 0) sm[tid>>6] = m;
  __syncthreads();
  m = fmaxf(fmaxf(sm[0],sm[1]), fmaxf(sm[2],sm[3]));
  float e0 = __expf(v.x-m), e1 = __expf(v.y-m), e2 = __expf(v.z-m), e3 = __expf(v.w-m);
  float s = e0+e1+e2+e3;
  for (int o = 32; o; o >>= 1) s += __shfl_xor(s, o);
  if ((tid & 63) == 0) ss[tid>>6] = s;
  __syncthreads();
  s = ss[0]+ss[1]+ss[2]+ss[3];
  float inv = 1.f/s;
  ((float4*)p)[tid] = make_float4(e0*inv, e1*inv, e2*inv, e3*inv);
}

// ---------------- PV: ob[i][h*32+d] = bf16(sum_j attn[h][i][j] * v[j][h*32+d])
__global__ void pv_k(const float* __restrict__ Smat, const short* __restrict__ vb,
                     short* __restrict__ ob) {
  __shared__ float as[32][64];
  __shared__ float vs[64][33];
  int tid = threadIdx.x;
  int hh = blockIdx.y;
  int i0 = blockIdx.x*32;
  int d = tid & 31;
  int ig = tid >> 5;
  float acc[4] = {0,0,0,0};
  for (int j0 = 0; j0 < N; j0 += 64) {
    __syncthreads();
    {
      int r = tid >> 3; int c = (tid & 7)*8;
      const float* src = Smat + ((size_t)hh*N + i0 + r)*N + j0 + c;
      float4 a0 = *(const float4*)src;
      float4 a1 = *(const float4*)(src+4);
      as[r][c]=a0.x; as[r][c+1]=a0.y; as[r][c+2]=a0.z; as[r][c+3]=a0.w;
      as[r][c+4]=a1.x; as[r][c+5]=a1.y; as[r][c+6]=a1.z; as[r][c+7]=a1.w;
    }
    {
      int r = tid >> 2; int c = (tid & 3)*8;
      bf16x8 vv = *(const bf16x8*)(vb + (size_t)(j0+r)*HID + hh*DH + c);
      #pragma unroll
      for (int u = 0; u < 8; ++u) vs[r][c+u] = (float)vv[u];
    }
    __syncthreads();
    for (int jj = 0; jj < 64; ++jj) {
      float vv = vs[jj][d];
      #pragma unroll
      for (int r = 0; r < 4; ++r) acc[r] += as[ig*4+r][jj]*vv;
    }
  }
  #pragma unroll
  for (int r = 0; r < 4; ++r)
    ob[(size_t)(i0+ig*4+r)*HID + hh*DH + d] = f2bf(acc[r]);
}

// ---------------- residual + layernorm (+ optional bf16 copy) ----------------
__global__ void add_ln_k(const float* __restrict__ a, const float* __restrict__ b,
                         const float* __restrict__ g, const float* __restrict__ be,
                         float* __restrict__ out, short* __restrict__ outb) {
  int i = blockIdx.x; int tid = threadIdx.x;
  float4 av = ((const float4*)(a + (size_t)i*HID))[tid];
  float4 bv = ((const float4*)(b + (size_t)i*HID))[tid];
  float4 v;
  v.x = av.x+bv.x; v.y = av.y+bv.y; v.z = av.z+bv.z; v.w = av.w+bv.w;
  float s = v.x+v.y+v.z+v.w;
  float s2 = v.x*v.x+v.y*v.y+v.z*v.z+v.w*v.w;
  for (int o = 32; o; o >>= 1) { s += __shfl_xor(s, o); s2 += __shfl_xor(s2, o); }
  __shared__ float sa[2], sb[2];
  if ((tid & 63) == 0) { sa[tid>>6] = s; sb[tid>>6] = s2; }
  __syncthreads();
  s = sa[0]+sa[1]; s2 = sb[0]+sb[1];
  float mean = s*(1.f/HID);
  float var = s2*(1.f/HID) - mean*mean;
  float rinv = rsqrtf(var + 1e-5f);
  float4 gv = ((const float4*)g)[tid];
  float4 bev = ((const float4*)be)[tid];
  float4 r;
  r.x = (v.x-mean)*rinv*gv.x + bev.x;
  r.y = (v.y-mean)*rinv*gv.y + bev.y;
  r.z = (v.z-mean)*rinv*gv.z + bev.z;
  r.w = (v.w-mean)*rinv*gv.w + bev.w;
  ((float4*)(out + (size_t)i*HID))[tid] = r;
  if (outb) {
    short4v o = { f2bf(r.x), f2bf(r.y), f2bf(r.z), f2bf(r.w) };
    ((short4v*)(outb + (size_t)i*HID))[tid] = o;
  }
}

extern "C" void kernel_launch(void* const* d_in, const int* in_sizes, int n_in,
                              void* d_out, int out_size, void* d_ws, size_t ws_size,
                              hipStream_t stream) {
  const float* x            = (const float*)d_in[0];
  const int*   spatial_pos  = (const int*)d_in[1];
  const int*   edge_input   = (const int*)d_in[2];
  const int*   in_degree    = (const int*)d_in[3];
  const int*   out_degree   = (const int*)d_in[4];
  const float* spatial_emb  = (const float*)d_in[5];
  const float* edge_emb     = (const float*)d_in[6];
  const float* edge_pos_emb = (const float*)d_in[7];
  const float* in_deg_emb   = (const float*)d_in[8];
  const float* out_deg_emb  = (const float*)d_in[9];
  const float* Wq = (const float*)d_in[10]; const float* bq = (const float*)d_in[11];
  const float* Wk = (const float*)d_in[12]; const float* bk = (const float*)d_in[13];
  const float* Wv = (const float*)d_in[14]; const float* bv = (const float*)d_in[15];
  const float* Wo = (const float*)d_in[16]; const float* bo = (const float*)d_in[17];
  const float* W1 = (const float*)d_in[18]; const float* b1 = (const float*)d_in[19];
  const float* W2 = (const float*)d_in[20]; const float* b2 = (const float*)d_in[21];
  const float* g1 = (const float*)d_in[22]; const float* be1 = (const float*)d_in[23];
  const float* g2 = (const float*)d_in[24]; const float* be2 = (const float*)d_in[25];

  char* W = (char*)d_ws;
  float* S    = (float*)W;                          // 64 MB
  float* h    = (float*)(W + 67108864);             // 2 MB
  float* y    = (float*)(W + 69206016);             // 2 MB
  float* h1   = (float*)(W + 71303168);             // 2 MB
  float* T    = (float*)(W + 73400320);             // 262400 B
  short* hb   = (short*)(W + 73662720);             // 1 MB
  short* qb   = (short*)(W + 74711296);             // 1 MB (ob aliases after scores)
  short* kb   = (short*)(W + 75759872);             // 1 MB (h1b aliases after scores)
  short* vb   = (short*)(W + 76808448);             // 1 MB
  short* midb = (short*)(W + 77857024);             // 2 MB
  short* Wtq  = (short*)(W + 79954176);             // 512 KB
  short* Wtk  = (short*)(W + 80478464);             // 512 KB
  short* Wtv  = (short*)(W + 81002752);             // 512 KB
  short* Wto  = (short*)(W + 81527040);             // 512 KB  (end 82,051,328)
  short* Wt1  = (short*)W;                          // aliases S (after pv done)
  short* Wt2  = (short*)(W + 1048576);              // aliases S
  short* ob   = qb;
  short* h1b  = kb;
  float* f2   = h;                                  // aliases h (after add_ln1)
  float* out  = (float*)d_out;
  const float SQS = 5.65685424949238019521f;        // sqrt(DH)

  centrality_k<<<N, 128, 0, stream>>>(x, in_degree, out_degree, in_deg_emb, out_deg_emb, h, hb);
  edge_table_k<<<(NEDGE*64 + 255)/256, 256, 0, stream>>>(edge_emb, edge_pos_emb, T);
  bias_k<<<(N*N)/256, 256, 0, stream>>>(spatial_pos, edge_input, spatial_emb, T, S);

  wtr_k<<<dim3(16,16), 256, 0, stream>>>(Wq, Wtq, 512, 512);
  wtr_k<<<dim3(16,16), 256, 0, stream>>>(Wk, Wtk, 512, 512);
  wtr_k<<<dim3(16,16), 256, 0, stream>>>(Wv, Wtv, 512, 512);
  wtr_k<<<dim3(16,16), 256, 0, stream>>>(Wo, Wto, 512, 512);

  gemm_mfma<32,0,0,1><<<dim3(16,16), 256, 0, stream>>>(hb, Wtq, bq, SQS, nullptr, qb, 512, 512);
  gemm_mfma<32,0,0,1><<<dim3(16,16), 256, 0, stream>>>(hb, Wtk, bk, 1.f, nullptr, kb, 512, 512);
  gemm_mfma<32,0,0,1><<<dim3(16,16), 256, 0, stream>>>(hb, Wtv, bv, 1.f, nullptr, vb, 512, 512);

  scores_mfma<<<dim3(16,16,16), 256, 0, stream>>>(qb, kb, S);
  softmax_k<<<NH*N, 256, 0, stream>>>(S);
  pv_k<<<dim3(N/32, NH), 256, 0, stream>>>(S, vb, ob);

  gemm_mfma<32,0,1,0><<<dim3(16,16), 256, 0, stream>>>(ob, Wto, bo, 1.f, y, nullptr, 512, 512);
  add_ln_k<<<N, 128, 0, stream>>>(h, y, g1, be1, h1, h1b);

  wtr_k<<<dim3(32,16), 256, 0, stream>>>(W1, Wt1, 512, 1024);
  wtr_k<<<dim3(16,32), 256, 0, stream>>>(W2, Wt2, 1024, 512);

  gemm_mfma<64,1,0,1><<<dim3(16,16), 256, 0, stream>>>(h1b, Wt1, b1, 1.f, nullptr, midb, 512, 1024);
  gemm_mfma<32,0,1,0><<<dim3(16,16), 256, 0, stream>>>(midb, Wt2, b2, 1.f, f2, nullptr, 1024, 512);
  add_ln_k<<<N, 128, 0, stream>>>(h1, f2, g2, be2, out, nullptr);
}

// Round 3
// 134.236 us; speedup vs baseline: 3.5550x; 1.6176x over previous
//
#include <hip/hip_runtime.h>
#include <math.h>

#define N 1024
#define HID 512
#define NH 16
#define DH 32
#define NEDGE 1025

typedef __attribute__((ext_vector_type(8))) __bf16 bf16x8;
typedef __attribute__((ext_vector_type(8))) unsigned short u16x8;
typedef __attribute__((ext_vector_type(4))) short short4v;
typedef __attribute__((ext_vector_type(4))) float f32x4;

__device__ inline short f2bf(float f) {
  unsigned u = __builtin_bit_cast(unsigned, f);
  u += 0x7fffu + ((u >> 16) & 1u);
  return (short)(u >> 16);
}
__device__ inline float bf2fu(unsigned short s) {
  unsigned u = ((unsigned)s) << 16;
  return __builtin_bit_cast(float, u);
}

// ---------------- centrality: h = x + ide[ind] + ode[outd]; also bf16 copy ---
__global__ void centrality_k(const float* __restrict__ x, const int* __restrict__ ind,
                             const int* __restrict__ outd, const float* __restrict__ ide,
                             const float* __restrict__ ode, float* __restrict__ h,
                             short* __restrict__ hb) {
  int i = blockIdx.x; int t = threadIdx.x;
  int a = ind[i], b = outd[i];
  float4 xv = ((const float4*)(x + (size_t)i*HID))[t];
  float4 av = ((const float4*)(ide + (size_t)a*HID))[t];
  float4 bv = ((const float4*)(ode + (size_t)b*HID))[t];
  float4 r;
  r.x = xv.x+av.x+bv.x; r.y = xv.y+av.y+bv.y;
  r.z = xv.z+av.z+bv.z; r.w = xv.w+av.w+bv.w;
  ((float4*)(h + (size_t)i*HID))[t] = r;
  short4v o = { f2bf(r.x), f2bf(r.y), f2bf(r.z), f2bf(r.w) };
  ((short4v*)(hb + (size_t)i*HID))[t] = o;
}

// ---------------- tables: Tb[e][k][h]=bf16(sum_d ee[e][d]*pw[k][d][h]); seb ---
__global__ void prep_tables(const float* __restrict__ ee, const float* __restrict__ epe,
                            const float* __restrict__ se,
                            short* __restrict__ Tb, short* __restrict__ seb) {
  int t = blockIdx.x*256 + threadIdx.x;
  if (t < NEDGE*64) {
    int e = t >> 6; int r = t & 63; int k = r >> 4; int hh = r & 15;
    const float* erow = ee + (size_t)e*32;
    const float* w = epe + k*512 + hh;
    float acc = 0.f;
    #pragma unroll
    for (int d = 0; d < 32; ++d) acc += erow[d] * w[d*16];
    Tb[t] = f2bf(acc);
  }
  if (t < 512*16) seb[t] = f2bf(se[t]);
}

// ---------------- weight transpose + bf16: Wt[n][k] = bf16(Win[k][n]) --------
__global__ void wtr_k(const float* __restrict__ Win, short* __restrict__ Wt, int K, int Nc) {
  __shared__ float tile[32][33];
  int n0 = blockIdx.x*32, k0 = blockIdx.y*32;
  int tid = threadIdx.x;
  int r = tid >> 3, c = (tid & 7) * 4;
  float4 v = *(const float4*)(Win + (size_t)(k0+r)*Nc + n0 + c);
  tile[r][c]=v.x; tile[r][c+1]=v.y; tile[r][c+2]=v.z; tile[r][c+3]=v.w;
  __syncthreads();
  short4v o = { f2bf(tile[c+0][r]), f2bf(tile[c+1][r]), f2bf(tile[c+2][r]), f2bf(tile[c+3][r]) };
  *(short4v*)(Wt + (size_t)(n0+r)*K + k0 + c) = o;
}

// ---------------- MFMA GEMM: C[M][Nc] = A[M][K](bf16) @ Bt[Nc][K]^T + bias ---
// OUT: 0 = f32 rows, 1 = bf16 rows, 2 = bf16 transposed (Vt[c][row])
template<int BN, int RELU, int OUT>
__launch_bounds__(256)
__global__ void gemm_mfma(const short* __restrict__ A, const short* __restrict__ Bt,
                          const float* __restrict__ bias, float scale,
                          float* __restrict__ Cf, short* __restrict__ Cb,
                          int K, int Nc) {
  __shared__ short As[64*64];
  __shared__ short Bs[BN*64];
  constexpr int WN = BN/32;
  constexpr int WM = 4/WN;
  constexpr int MI = 64/(WM*16);
  int tid = threadIdx.x;
  int w = tid >> 6, l = tid & 63;
  int lr = l & 15, kg = l >> 4;
  int wn = (WN == 1) ? 0 : (w & 1);
  int wm = (WN == 1) ? w : (w >> 1);
  int i0 = blockIdx.y*64, n0 = blockIdx.x*BN;
  int srow = tid >> 3, sslot = tid & 7;
  f32x4 acc[MI][2];
  #pragma unroll
  for (int mi=0; mi<MI; ++mi)
    #pragma unroll
    for (int ni=0; ni<2; ++ni) acc[mi][ni] = (f32x4){0.f,0.f,0.f,0.f};
  const short* Ag = A + (size_t)i0*K;
  const short* Bg = Bt + (size_t)n0*K;
  for (int k0 = 0; k0 < K; k0 += 64) {
    bf16x8 va0 = *(const bf16x8*)(Ag + (size_t)srow*K + k0 + sslot*8);
    bf16x8 va1 = *(const bf16x8*)(Ag + (size_t)(srow+32)*K + k0 + sslot*8);
    bf16x8 vb0 = *(const bf16x8*)(Bg + (size_t)srow*K + k0 + sslot*8);
    bf16x8 vb1;
    if (BN == 64) vb1 = *(const bf16x8*)(Bg + (size_t)(srow+32)*K + k0 + sslot*8);
    __syncthreads();
    *(bf16x8*)((char*)As + srow*128 + ((sslot ^ (srow&7))<<4)) = va0;
    *(bf16x8*)((char*)As + (srow+32)*128 + ((sslot ^ (srow&7))<<4)) = va1;
    *(bf16x8*)((char*)Bs + srow*128 + ((sslot ^ (srow&7))<<4)) = vb0;
    if (BN == 64)
      *(bf16x8*)((char*)Bs + (srow+32)*128 + ((sslot ^ (srow&7))<<4)) = vb1;
    __syncthreads();
    #pragma unroll
    for (int ks = 0; ks < 2; ++ks) {
      bf16x8 fa[MI], fb[2];
      #pragma unroll
      for (int mi=0; mi<MI; ++mi) {
        int r = wm*(64/WM) + mi*16 + lr;
        fa[mi] = *(const bf16x8*)((const char*)As + r*128 + (((ks*4+kg) ^ (r&7))<<4));
      }
      #pragma unroll
      for (int ni=0; ni<2; ++ni) {
        int r = wn*32 + ni*16 + lr;
        fb[ni] = *(const bf16x8*)((const char*)Bs + r*128 + (((ks*4+kg) ^ (r&7))<<4));
      }
      #pragma unroll
      for (int mi=0; mi<MI; ++mi)
        #pragma unroll
        for (int ni=0; ni<2; ++ni)
          acc[mi][ni] = __builtin_amdgcn_mfma_f32_16x16x32_bf16(fa[mi], fb[ni], acc[mi][ni], 0, 0, 0);
    }
  }
  #pragma unroll
  for (int mi=0; mi<MI; ++mi) {
    #pragma unroll
    for (int ni=0; ni<2; ++ni) {
      int c = n0 + wn*32 + ni*16 + lr;
      float bb = bias[c];
      float vv[4];
      #pragma unroll
      for (int r=0; r<4; ++r) {
        float v = (acc[mi][ni][r] + bb) * scale;
        if (RELU) v = fmaxf(v, 0.f);
        vv[r] = v;
      }
      int rr0 = i0 + wm*(64/WM) + mi*16 + kg*4;
      if (OUT == 0) {
        #pragma unroll
        for (int r=0; r<4; ++r) Cf[(size_t)(rr0+r)*Nc + c] = vv[r];
      } else if (OUT == 1) {
        #pragma unroll
        for (int r=0; r<4; ++r) Cb[(size_t)(rr0+r)*Nc + c] = f2bf(vv[r]);
      } else {
        short4v o = { f2bf(vv[0]), f2bf(vv[1]), f2bf(vv[2]), f2bf(vv[3]) };
        *(short4v*)(Cb + (size_t)c*N + rr0) = o;   // Vt[c][row]
      }
    }
  }
}

// ---------------- fused flash attention with Graphormer bias -----------------
// grid (8 j-chunks, 64 i-tiles), 256 threads. wave w handles heads 4w..4w+3.
__launch_bounds__(256)
__global__ void fused_attn(const short* __restrict__ qb, const short* __restrict__ kb,
                           const short* __restrict__ Vt, const int* __restrict__ sp,
                           const int* __restrict__ ei, const short* __restrict__ seb,
                           const short* __restrict__ Tb,
                           float* __restrict__ Pm, float* __restrict__ Pl,
                           float* __restrict__ Po) {
  __shared__ unsigned bias_lds[8*1024];   // [hp][j(64)][i(16)] packed 2 heads
  int tid = threadIdx.x;
  int w = tid >> 6, l = tid & 63, lr = l & 15, kg = l >> 4;
  int i0 = blockIdx.y*16;
  int jc = blockIdx.x;
  // Q fragments (scaled by sqrt(DH) already in qb)
  bf16x8 qf[4];
  #pragma unroll
  for (int hh=0; hh<4; ++hh)
    qf[hh] = *(const bf16x8*)(qb + (size_t)(i0+lr)*HID + (w*4+hh)*DH + kg*8);
  float m[4]    = {-INFINITY,-INFINITY,-INFINITY,-INFINITY};
  float lsum[4] = {0.f,0.f,0.f,0.f};
  f32x4 accO[4][2];
  #pragma unroll
  for (int hh=0; hh<4; ++hh) { accO[hh][0] = (f32x4){0,0,0,0}; accO[hh][1] = (f32x4){0,0,0,0}; }

  for (int jt=0; jt<2; ++jt) {
    int j0 = jc*128 + jt*64;
    __syncthreads();                      // previous bias consumers done
    // ---- phase A: cooperative bias tile (16 heads x 64 j x 16 i) ----
    #pragma unroll
    for (int pp=0; pp<4; ++pp) {
      int p = tid + pp*256;
      int jj = p >> 4, ii = p & 15;
      size_t pidx = (size_t)(i0+ii)*N + (j0+jj);
      int4 e = ((const int4*)ei)[pidx];
      int spv = sp[pidx];
      int cnt = (e.x!=0)+(e.y!=0)+(e.z!=0)+(e.w!=0);
      float inv = 1.f/(float)(cnt>0?cnt:1);
      u16x8 t0a = *(const u16x8*)(Tb + (size_t)e.x*64);
      u16x8 t0b = *(const u16x8*)(Tb + (size_t)e.x*64 + 8);
      u16x8 t1a = *(const u16x8*)(Tb + (size_t)e.y*64 + 16);
      u16x8 t1b = *(const u16x8*)(Tb + (size_t)e.y*64 + 24);
      u16x8 t2a = *(const u16x8*)(Tb + (size_t)e.z*64 + 32);
      u16x8 t2b = *(const u16x8*)(Tb + (size_t)e.z*64 + 40);
      u16x8 t3a = *(const u16x8*)(Tb + (size_t)e.w*64 + 48);
      u16x8 t3b = *(const u16x8*)(Tb + (size_t)e.w*64 + 56);
      u16x8 sa  = *(const u16x8*)(seb + (size_t)spv*16);
      u16x8 sb  = *(const u16x8*)(seb + (size_t)spv*16 + 8);
      float v16[16];
      #pragma unroll
      for (int q2=0; q2<8; ++q2) {
        float ta = bf2fu(t0a[q2]) + bf2fu(t1a[q2]) + bf2fu(t2a[q2]) + bf2fu(t3a[q2]);
        v16[q2]   = ta*inv + bf2fu(sa[q2]);
        float tb = bf2fu(t0b[q2]) + bf2fu(t1b[q2]) + bf2fu(t2b[q2]) + bf2fu(t3b[q2]);
        v16[8+q2] = tb*inv + bf2fu(sb[q2]);
      }
      #pragma unroll
      for (int hp=0; hp<8; ++hp) {
        unsigned lo = (unsigned)(unsigned short)f2bf(v16[2*hp]);
        unsigned hi = (unsigned)(unsigned short)f2bf(v16[2*hp+1]);
        bias_lds[hp*1024 + p] = (hi<<16) | lo;
      }
    }
    __syncthreads();
    // ---- phase B: per-wave, 4 heads ----
    #pragma unroll
    for (int hh=0; hh<4; ++hh) {
      int h = w*4 + hh;
      bf16x8 kf[4];
      #pragma unroll
      for (int mi=0; mi<4; ++mi)
        kf[mi] = *(const bf16x8*)(kb + (size_t)(j0+mi*16+lr)*HID + h*DH + kg*8);
      f32x4 s[4];
      #pragma unroll
      for (int mi=0; mi<4; ++mi)
        s[mi] = __builtin_amdgcn_mfma_f32_16x16x32_bf16(kf[mi], qf[hh], (f32x4){0,0,0,0}, 0, 0, 0);
      float pm = -INFINITY;
      #pragma unroll
      for (int mi=0; mi<4; ++mi) {
        #pragma unroll
        for (int r=0; r<4; ++r) {
          unsigned u = bias_lds[(h>>1)*1024 + (mi*16+kg*4+r)*16 + lr];
          float b = bf2fu((unsigned short)((h&1) ? (u>>16) : (u & 0xffff)));
          s[mi][r] += b;
          pm = fmaxf(pm, s[mi][r]);
        }
      }
      pm = fmaxf(pm, __shfl_xor(pm, 16));
      pm = fmaxf(pm, __shfl_xor(pm, 32));
      float newm = fmaxf(m[hh], pm);
      float fac = __expf(m[hh] - newm);
      float ev[4][4];
      float ts = 0.f;
      #pragma unroll
      for (int mi=0; mi<4; ++mi)
        #pragma unroll
        for (int r=0; r<4; ++r) { float e_ = __expf(s[mi][r] - newm); ev[mi][r] = e_; ts += e_; }
      ts += __shfl_xor(ts, 16);
      ts += __shfl_xor(ts, 32);
      lsum[hh] = lsum[hh]*fac + ts;
      m[hh] = newm;
      #pragma unroll
      for (int mi=0; mi<2; ++mi)
        #pragma unroll
        for (int r=0; r<4; ++r) accO[hh][mi][r] *= fac;
      // pack P (bf16 pairs): u01[mi][pr] = (ev[mi][2pr+1], ev[mi][2pr])
      unsigned u01[4][2];
      #pragma unroll
      for (int mi=0; mi<4; ++mi) {
        #pragma unroll
        for (int pr=0; pr<2; ++pr) {
          unsigned lo = (unsigned)(unsigned short)f2bf(ev[mi][2*pr]);
          unsigned hi = (unsigned)(unsigned short)f2bf(ev[mi][2*pr+1]);
          u01[mi][pr] = (hi<<16) | lo;
        }
      }
      // redistribute to B-frag layout and PV
      #pragma unroll
      for (int ks=0; ks<2; ++ks) {
        unsigned Wd[4];
        #pragma unroll
        for (int wd=0; wd<4; ++wd) {
          int srcLane = lr + ((2*(kg&1) + (wd>>1)) << 4);
          int a = __shfl((int)u01[2*ks][wd&1],   srcLane);
          int b = __shfl((int)u01[2*ks+1][wd&1], srcLane);
          Wd[wd] = (kg>>1) ? (unsigned)b : (unsigned)a;
        }
        union { unsigned u[4]; bf16x8 v; } cvt;
        cvt.u[0]=Wd[0]; cvt.u[1]=Wd[1]; cvt.u[2]=Wd[2]; cvt.u[3]=Wd[3];
        bf16x8 pfrag = cvt.v;
        #pragma unroll
        for (int mi=0; mi<2; ++mi) {
          bf16x8 vf = *(const bf16x8*)(Vt + (size_t)(h*DH + mi*16 + lr)*N + j0 + ks*32 + kg*8);
          accO[hh][mi] = __builtin_amdgcn_mfma_f32_16x16x32_bf16(vf, pfrag, accO[hh][mi], 0, 0, 0);
        }
      }
    }
  }
  // ---- write partials ----
  #pragma unroll
  for (int hh=0; hh<4; ++hh) {
    int h = w*4 + hh;
    if (kg == 0) {
      Pm[(size_t)(jc*16+h)*N + i0 + lr] = m[hh];
      Pl[(size_t)(jc*16+h)*N + i0 + lr] = lsum[hh];
    }
    #pragma unroll
    for (int mi=0; mi<2; ++mi)
      #pragma unroll
      for (int r=0; r<4; ++r) {
        int d = mi*16 + kg*4 + r;
        Po[((size_t)(jc*16+h)*DH + d)*N + i0 + lr] = accO[hh][mi][r];
      }
  }
}

// ---------------- combine partials -> ob (bf16 [i][h*32+d]) ------------------
__global__ void attn_combine(const float* __restrict__ Pm, const float* __restrict__ Pl,
                             const float* __restrict__ Po, short* __restrict__ ob) {
  int bx = blockIdx.x;
  int h0 = (bx >> 4) * 4;
  int i0 = (bx & 15) * 64;
  int tid = threadIdx.x;
  int i = i0 + (tid & 63);
  int h = h0 + (tid >> 6);
  float mc[8];
  float M = -INFINITY;
  #pragma unroll
  for (int c=0; c<8; ++c) { mc[c] = Pm[(size_t)(c*16+h)*N + i]; M = fmaxf(M, mc[c]); }
  float wc[8]; float L = 0.f;
  #pragma unroll
  for (int c=0; c<8; ++c) { wc[c] = __expf(mc[c]-M); L += Pl[(size_t)(c*16+h)*N + i]*wc[c]; }
  float invL = 1.f / L;
  #pragma unroll
  for (int d0=0; d0<DH; d0+=4) {
    float o[4] = {0,0,0,0};
    #pragma unroll
    for (int c=0; c<8; ++c) {
      #pragma unroll
      for (int dd=0; dd<4; ++dd)
        o[dd] += wc[c] * Po[((size_t)(c*16+h)*DH + d0+dd)*N + i];
    }
    short4v st = { f2bf(o[0]*invL), f2bf(o[1]*invL), f2bf(o[2]*invL), f2bf(o[3]*invL) };
    *(short4v*)(ob + (size_t)i*HID + h*DH + d0) = st;
  }
}

// ---------------- residual + layernorm (+ optional bf16 copy) ----------------
__global__ void add_ln_k(const float* __restrict__ a, const float* __restrict__ b,
                         const float* __restrict__ g, const float* __restrict__ be,
                         float* __restrict__ out, short* __restrict__ outb) {
  int i = blockIdx.x; int tid = threadIdx.x;
  float4 av = ((const float4*)(a + (size_t)i*HID))[tid];
  float4 bv = ((const float4*)(b + (size_t)i*HID))[tid];
  float4 v;
  v.x = av.x+bv.x; v.y = av.y+bv.y; v.z = av.z+bv.z; v.w = av.w+bv.w;
  float s = v.x+v.y+v.z+v.w;
  float s2 = v.x*v.x+v.y*v.y+v.z*v.z+v.w*v.w;
  for (int o = 32; o; o >>= 1) { s += __shfl_xor(s, o); s2 += __shfl_xor(s2, o); }
  __shared__ float sa[2], sb[2];
  if ((tid & 63) == 0) { sa[tid>>6] = s; sb[tid>>6] = s2; }
  __syncthreads();
  s = sa[0]+sa[1]; s2 = sb[0]+sb[1];
  float mean = s*(1.f/HID);
  float var = s2*(1.f/HID) - mean*mean;
  float rinv = rsqrtf(var + 1e-5f);
  float4 gv = ((const float4*)g)[tid];
  float4 bev = ((const float4*)be)[tid];
  float4 r;
  r.x = (v.x-mean)*rinv*gv.x + bev.x;
  r.y = (v.y-mean)*rinv*gv.y + bev.y;
  r.z = (v.z-mean)*rinv*gv.z + bev.z;
  r.w = (v.w-mean)*rinv*gv.w + bev.w;
  ((float4*)(out + (size_t)i*HID))[tid] = r;
  if (outb) {
    short4v o = { f2bf(r.x), f2bf(r.y), f2bf(r.z), f2bf(r.w) };
    ((short4v*)(outb + (size_t)i*HID))[tid] = o;
  }
}

extern "C" void kernel_launch(void* const* d_in, const int* in_sizes, int n_in,
                              void* d_out, int out_size, void* d_ws, size_t ws_size,
                              hipStream_t stream) {
  const float* x            = (const float*)d_in[0];
  const int*   spatial_pos  = (const int*)d_in[1];
  const int*   edge_input   = (const int*)d_in[2];
  const int*   in_degree    = (const int*)d_in[3];
  const int*   out_degree   = (const int*)d_in[4];
  const float* spatial_emb  = (const float*)d_in[5];
  const float* edge_emb     = (const float*)d_in[6];
  const float* edge_pos_emb = (const float*)d_in[7];
  const float* in_deg_emb   = (const float*)d_in[8];
  const float* out_deg_emb  = (const float*)d_in[9];
  const float* Wq = (const float*)d_in[10]; const float* bq = (const float*)d_in[11];
  const float* Wk = (const float*)d_in[12]; const float* bk = (const float*)d_in[13];
  const float* Wv = (const float*)d_in[14]; const float* bv = (const float*)d_in[15];
  const float* Wo = (const float*)d_in[16]; const float* bo = (const float*)d_in[17];
  const float* W1 = (const float*)d_in[18]; const float* b1 = (const float*)d_in[19];
  const float* W2 = (const float*)d_in[20]; const float* b2 = (const float*)d_in[21];
  const float* g1 = (const float*)d_in[22]; const float* be1 = (const float*)d_in[23];
  const float* g2 = (const float*)d_in[24]; const float* be2 = (const float*)d_in[25];

  char* W = (char*)d_ws;
  short* Tb   = (short*)(W + 0);            // 131,200 B
  short* seb  = (short*)(W + 262144);       // 16 KB
  float* h    = (float*)(W + 524288);       // 2 MB
  float* y    = (float*)(W + 2621440);      // 2 MB
  float* h1   = (float*)(W + 4718592);      // 2 MB
  short* hb   = (short*)(W + 6815744);      // 1 MB
  short* qb   = (short*)(W + 7864320);      // 1 MB
  short* kb   = (short*)(W + 8912896);      // 1 MB
  short* Vt   = (short*)(W + 9961472);      // 1 MB
  short* ob   = (short*)(W + 11010048);     // 1 MB
  short* h1b  = (short*)(W + 12058624);     // 1 MB
  short* midb = (short*)(W + 13107200);     // 2 MB
  float* f2   = (float*)(W + 15204352);     // 2 MB
  short* Wtq  = (short*)(W + 17301504);     // 512 KB
  short* Wtk  = (short*)(W + 17825792);
  short* Wtv  = (short*)(W + 18350080);
  short* Wto  = (short*)(W + 18874368);
  short* Wt1  = (short*)(W + 19398656);     // 1 MB
  short* Wt2  = (short*)(W + 20447232);     // 1 MB
  float* Pm   = (float*)(W + 21495808);     // 512 KB
  float* Pl   = (float*)(W + 22020096);     // 512 KB
  float* Po   = (float*)(W + 22544384);     // 16 MB -> ends 39,321,600
  float* out  = (float*)d_out;
  const float SQS = 5.65685424949238019521f;

  centrality_k<<<N, 128, 0, stream>>>(x, in_degree, out_degree, in_deg_emb, out_deg_emb, h, hb);
  prep_tables<<<257, 256, 0, stream>>>(edge_emb, edge_pos_emb, spatial_emb, Tb, seb);

  wtr_k<<<dim3(16,16), 256, 0, stream>>>(Wq, Wtq, 512, 512);
  wtr_k<<<dim3(16,16), 256, 0, stream>>>(Wk, Wtk, 512, 512);
  wtr_k<<<dim3(16,16), 256, 0, stream>>>(Wv, Wtv, 512, 512);
  wtr_k<<<dim3(16,16), 256, 0, stream>>>(Wo, Wto, 512, 512);
  wtr_k<<<dim3(32,16), 256, 0, stream>>>(W1, Wt1, 512, 1024);
  wtr_k<<<dim3(16,32), 256, 0, stream>>>(W2, Wt2, 1024, 512);

  gemm_mfma<32,0,1><<<dim3(16,16), 256, 0, stream>>>(hb, Wtq, bq, SQS, nullptr, qb, 512, 512);
  gemm_mfma<32,0,1><<<dim3(16,16), 256, 0, stream>>>(hb, Wtk, bk, 1.f, nullptr, kb, 512, 512);
  gemm_mfma<32,0,2><<<dim3(16,16), 256, 0, stream>>>(hb, Wtv, bv, 1.f, nullptr, Vt, 512, 512);

  fused_attn<<<dim3(8,64), 256, 0, stream>>>(qb, kb, Vt, spatial_pos, edge_input, seb, Tb,
                                             Pm, Pl, Po);
  attn_combine<<<64, 256, 0, stream>>>(Pm, Pl, Po, ob);

  gemm_mfma<32,0,0><<<dim3(16,16), 256, 0, stream>>>(ob, Wto, bo, 1.f, y, nullptr, 512, 512);
  add_ln_k<<<N, 128, 0, stream>>>(h, y, g1, be1, h1, h1b);
  gemm_mfma<64,1,1><<<dim3(16,16), 256, 0, stream>>>(h1b, Wt1, b1, 1.f, nullptr, midb, 512, 1024);
  gemm_mfma<32,0,0><<<dim3(16,16), 256, 0, stream>>>(midb, Wt2, b2, 1.f, f2, nullptr, 1024, 512);
  add_ln_k<<<N, 128, 0, stream>>>(h1, f2, g2, be2, out, nullptr);
}

// Round 4
// 116.368 us; speedup vs baseline: 4.1008x; 1.1535x over previous
//
#include <hip/hip_runtime.h>
#include <math.h>

#define N 1024
#define HID 512
#define NH 16
#define DH 32
#define NEDGE 1025

typedef __attribute__((ext_vector_type(8))) __bf16 bf16x8;
typedef __attribute__((ext_vector_type(8))) unsigned short u16x8;
typedef __attribute__((ext_vector_type(4))) short short4v;
typedef __attribute__((ext_vector_type(4))) float f32x4;

__device__ inline short f2bf(float f) {
  unsigned u = __builtin_bit_cast(unsigned, f);
  u += 0x7fffu + ((u >> 16) & 1u);
  return (short)(u >> 16);
}
__device__ inline float bf2fu(unsigned short s) {
  unsigned u = ((unsigned)s) << 16;
  return __builtin_bit_cast(float, u);
}

// ---------------- centrality: h = x + ide[ind] + ode[outd]; also bf16 copy ---
__global__ void centrality_k(const float* __restrict__ x, const int* __restrict__ ind,
                             const int* __restrict__ outd, const float* __restrict__ ide,
                             const float* __restrict__ ode, float* __restrict__ h,
                             short* __restrict__ hb) {
  int i = blockIdx.x; int t = threadIdx.x;
  int a = ind[i], b = outd[i];
  float4 xv = ((const float4*)(x + (size_t)i*HID))[t];
  float4 av = ((const float4*)(ide + (size_t)a*HID))[t];
  float4 bv = ((const float4*)(ode + (size_t)b*HID))[t];
  float4 r;
  r.x = xv.x+av.x+bv.x; r.y = xv.y+av.y+bv.y;
  r.z = xv.z+av.z+bv.z; r.w = xv.w+av.w+bv.w;
  ((float4*)(h + (size_t)i*HID))[t] = r;
  short4v o = { f2bf(r.x), f2bf(r.y), f2bf(r.z), f2bf(r.w) };
  ((short4v*)(hb + (size_t)i*HID))[t] = o;
}

// ---------------- tables: Tb[e][k][h]=bf16(sum_d ee[e][d]*pw[k][d][h]); seb ---
__global__ void prep_tables(const float* __restrict__ ee, const float* __restrict__ epe,
                            const float* __restrict__ se,
                            short* __restrict__ Tb, short* __restrict__ seb) {
  int t = blockIdx.x*256 + threadIdx.x;
  if (t < NEDGE*64) {
    int e = t >> 6; int r = t & 63; int k = r >> 4; int hh = r & 15;
    const float* erow = ee + (size_t)e*32;
    const float* w = epe + k*512 + hh;
    float acc = 0.f;
    #pragma unroll
    for (int d = 0; d < 32; ++d) acc += erow[d] * w[d*16];
    Tb[t] = f2bf(acc);
  }
  if (t < 512*16) seb[t] = f2bf(se[t]);
}

// ---------------- weight transpose + bf16: Wt[n][k] = bf16(Win[k][n]) --------
__device__ inline void wtr_body(const float* __restrict__ Win, short* __restrict__ Wt,
                                int K, int Nc) {
  __shared__ float tile[32][33];
  int n0 = blockIdx.x*32, k0 = blockIdx.y*32;
  int tid = threadIdx.x;
  int r = tid >> 3, c = (tid & 7) * 4;
  float4 v = *(const float4*)(Win + (size_t)(k0+r)*Nc + n0 + c);
  tile[r][c]=v.x; tile[r][c+1]=v.y; tile[r][c+2]=v.z; tile[r][c+3]=v.w;
  __syncthreads();
  short4v o = { f2bf(tile[c+0][r]), f2bf(tile[c+1][r]), f2bf(tile[c+2][r]), f2bf(tile[c+3][r]) };
  *(short4v*)(Wt + (size_t)(n0+r)*K + k0 + c) = o;
}
__global__ void wtr_k(const float* __restrict__ Win, short* __restrict__ Wt, int K, int Nc) {
  wtr_body(Win, Wt, K, Nc);
}
__global__ void wtr4_k(const float* __restrict__ W0, const float* __restrict__ W1_,
                       const float* __restrict__ W2_, const float* __restrict__ W3,
                       short* __restrict__ T0, short* __restrict__ T1,
                       short* __restrict__ T2, short* __restrict__ T3) {
  int z = blockIdx.z;
  const float* Win = z==0 ? W0 : z==1 ? W1_ : z==2 ? W2_ : W3;
  short* Wt = z==0 ? T0 : z==1 ? T1 : z==2 ? T2 : T3;
  wtr_body(Win, Wt, 512, 512);
}

// ---------------- MFMA GEMM: C[M][Nc] = A[M][K](bf16) @ Bt[Nc][K]^T + bias ---
// OUT: 0 = f32 rows, 1 = bf16 rows
template<int BN, int RELU, int OUT>
__launch_bounds__(256)
__global__ void gemm_mfma(const short* __restrict__ A, const short* __restrict__ Bt,
                          const float* __restrict__ bias, float scale,
                          float* __restrict__ Cf, short* __restrict__ Cb,
                          int K, int Nc) {
  __shared__ short As[64*64];
  __shared__ short Bs[BN*64];
  constexpr int WN = BN/32;
  constexpr int WM = 4/WN;
  constexpr int MI = 64/(WM*16);
  int tid = threadIdx.x;
  int w = tid >> 6, l = tid & 63;
  int lr = l & 15, kg = l >> 4;
  int wn = (WN == 1) ? 0 : (w & 1);
  int wm = (WN == 1) ? w : (w >> 1);
  int i0 = blockIdx.y*64, n0 = blockIdx.x*BN;
  int srow = tid >> 3, sslot = tid & 7;
  f32x4 acc[MI][2];
  #pragma unroll
  for (int mi=0; mi<MI; ++mi)
    #pragma unroll
    for (int ni=0; ni<2; ++ni) acc[mi][ni] = (f32x4){0.f,0.f,0.f,0.f};
  const short* Ag = A + (size_t)i0*K;
  const short* Bg = Bt + (size_t)n0*K;
  for (int k0 = 0; k0 < K; k0 += 64) {
    bf16x8 va0 = *(const bf16x8*)(Ag + (size_t)srow*K + k0 + sslot*8);
    bf16x8 va1 = *(const bf16x8*)(Ag + (size_t)(srow+32)*K + k0 + sslot*8);
    bf16x8 vb0 = *(const bf16x8*)(Bg + (size_t)srow*K + k0 + sslot*8);
    bf16x8 vb1;
    if (BN == 64) vb1 = *(const bf16x8*)(Bg + (size_t)(srow+32)*K + k0 + sslot*8);
    __syncthreads();
    *(bf16x8*)((char*)As + srow*128 + ((sslot ^ (srow&7))<<4)) = va0;
    *(bf16x8*)((char*)As + (srow+32)*128 + ((sslot ^ (srow&7))<<4)) = va1;
    *(bf16x8*)((char*)Bs + srow*128 + ((sslot ^ (srow&7))<<4)) = vb0;
    if (BN == 64)
      *(bf16x8*)((char*)Bs + (srow+32)*128 + ((sslot ^ (srow&7))<<4)) = vb1;
    __syncthreads();
    #pragma unroll
    for (int ks = 0; ks < 2; ++ks) {
      bf16x8 fa[MI], fb[2];
      #pragma unroll
      for (int mi=0; mi<MI; ++mi) {
        int r = wm*(64/WM) + mi*16 + lr;
        fa[mi] = *(const bf16x8*)((const char*)As + r*128 + (((ks*4+kg) ^ (r&7))<<4));
      }
      #pragma unroll
      for (int ni=0; ni<2; ++ni) {
        int r = wn*32 + ni*16 + lr;
        fb[ni] = *(const bf16x8*)((const char*)Bs + r*128 + (((ks*4+kg) ^ (r&7))<<4));
      }
      #pragma unroll
      for (int mi=0; mi<MI; ++mi)
        #pragma unroll
        for (int ni=0; ni<2; ++ni)
          acc[mi][ni] = __builtin_amdgcn_mfma_f32_16x16x32_bf16(fa[mi], fb[ni], acc[mi][ni], 0, 0, 0);
    }
  }
  #pragma unroll
  for (int mi=0; mi<MI; ++mi) {
    #pragma unroll
    for (int ni=0; ni<2; ++ni) {
      int c = n0 + wn*32 + ni*16 + lr;
      float bb = bias[c];
      float vv[4];
      #pragma unroll
      for (int r=0; r<4; ++r) {
        float v = (acc[mi][ni][r] + bb) * scale;
        if (RELU) v = fmaxf(v, 0.f);
        vv[r] = v;
      }
      int rr0 = i0 + wm*(64/WM) + mi*16 + kg*4;
      if (OUT == 0) {
        #pragma unroll
        for (int r=0; r<4; ++r) Cf[(size_t)(rr0+r)*Nc + c] = vv[r];
      } else {
        #pragma unroll
        for (int r=0; r<4; ++r) Cb[(size_t)(rr0+r)*Nc + c] = f2bf(vv[r]);
      }
    }
  }
}

// ---------------- batched Q/K/V GEMM (BN=32, K=Nc=512) ----------------------
__launch_bounds__(256)
__global__ void qkv_gemm(const short* __restrict__ A,
                         const short* __restrict__ Wtq, const short* __restrict__ Wtk,
                         const short* __restrict__ Wtv,
                         const float* __restrict__ bq, const float* __restrict__ bk,
                         const float* __restrict__ bv,
                         short* __restrict__ qb, short* __restrict__ kb,
                         short* __restrict__ Vt) {
  __shared__ short As[64*64];
  __shared__ short Bs[32*64];
  int z = blockIdx.z;
  const short* Bt = z==0 ? Wtq : z==1 ? Wtk : Wtv;
  const float* bias = z==0 ? bq : z==1 ? bk : bv;
  const float scale = z==0 ? 5.65685424949238019521f : 1.f;
  int tid = threadIdx.x;
  int w = tid >> 6, l = tid & 63, lr = l & 15, kg = l >> 4;
  int i0 = blockIdx.y*64, n0 = blockIdx.x*32;
  int srow = tid >> 3, sslot = tid & 7;
  f32x4 acc[2] = {(f32x4){0,0,0,0},(f32x4){0,0,0,0}};
  const short* Ag = A + (size_t)i0*512;
  const short* Bg = Bt + (size_t)n0*512;
  for (int k0 = 0; k0 < 512; k0 += 64) {
    bf16x8 va0 = *(const bf16x8*)(Ag + (size_t)srow*512 + k0 + sslot*8);
    bf16x8 va1 = *(const bf16x8*)(Ag + (size_t)(srow+32)*512 + k0 + sslot*8);
    bf16x8 vb0 = *(const bf16x8*)(Bg + (size_t)srow*512 + k0 + sslot*8);
    __syncthreads();
    *(bf16x8*)((char*)As + srow*128 + ((sslot ^ (srow&7))<<4)) = va0;
    *(bf16x8*)((char*)As + (srow+32)*128 + ((sslot ^ (srow&7))<<4)) = va1;
    *(bf16x8*)((char*)Bs + srow*128 + ((sslot ^ (srow&7))<<4)) = vb0;
    __syncthreads();
    #pragma unroll
    for (int ks = 0; ks < 2; ++ks) {
      int ra = w*16 + lr;
      bf16x8 fa = *(const bf16x8*)((const char*)As + ra*128 + (((ks*4+kg) ^ (ra&7))<<4));
      #pragma unroll
      for (int ni=0; ni<2; ++ni) {
        int rb = ni*16 + lr;
        bf16x8 fb = *(const bf16x8*)((const char*)Bs + rb*128 + (((ks*4+kg) ^ (rb&7))<<4));
        acc[ni] = __builtin_amdgcn_mfma_f32_16x16x32_bf16(fa, fb, acc[ni], 0, 0, 0);
      }
    }
  }
  short* Cb = z==0 ? qb : kb;
  #pragma unroll
  for (int ni=0; ni<2; ++ni) {
    int c = n0 + ni*16 + lr;
    float bb = bias[c];
    float vv[4];
    #pragma unroll
    for (int r=0; r<4; ++r) vv[r] = (acc[ni][r] + bb) * scale;
    int rr0 = i0 + w*16 + kg*4;
    if (z < 2) {
      #pragma unroll
      for (int r=0; r<4; ++r) Cb[(size_t)(rr0+r)*512 + c] = f2bf(vv[r]);
    } else {
      short4v o = { f2bf(vv[0]), f2bf(vv[1]), f2bf(vv[2]), f2bf(vv[3]) };
      *(short4v*)(Vt + (size_t)c*N + rr0) = o;   // Vt[c][row]
    }
  }
}

// ---------------- fused flash attention with Graphormer bias -----------------
// grid (8 j-chunks, 64 i-tiles), 512 threads (8 waves); wave w = heads 2w,2w+1.
__launch_bounds__(512)
__global__ void fused_attn(const short* __restrict__ qb, const short* __restrict__ kb,
                           const short* __restrict__ Vt, const int* __restrict__ sp,
                           const int* __restrict__ ei, const short* __restrict__ seb,
                           const short* __restrict__ Tb,
                           float* __restrict__ Pm, float* __restrict__ Pl,
                           float* __restrict__ Po) {
  __shared__ unsigned bias_lds[8*1024];   // [hp][ Q(j)*16 + (i ^ ((Q(j)>>1)&15)) ]
  int tid = threadIdx.x;
  int w = tid >> 6, l = tid & 63, lr = l & 15, kg = l >> 4;
  int i0 = blockIdx.y*16;
  int jc = blockIdx.x;
  bf16x8 qf[2];
  #pragma unroll
  for (int hh=0; hh<2; ++hh)
    qf[hh] = *(const bf16x8*)(qb + (size_t)(i0+lr)*HID + (w*2+hh)*DH + kg*8);
  float m[2]    = {-INFINITY,-INFINITY};
  float lsum[2] = {0.f,0.f};
  f32x4 accO[2][2];
  #pragma unroll
  for (int hh=0; hh<2; ++hh) { accO[hh][0] = (f32x4){0,0,0,0}; accO[hh][1] = (f32x4){0,0,0,0}; }

  for (int jt=0; jt<2; ++jt) {
    int j0 = jc*128 + jt*64;
    __syncthreads();                      // previous bias consumers done
    // ---- phase A: cooperative bias tile, j-fast (coalesced ei/sp) ----
    #pragma unroll
    for (int pp=0; pp<2; ++pp) {
      int p = pp*512 + tid;               // 0..1023
      int jj = p & 63, ii = p >> 6;
      size_t pidx = (size_t)(i0+ii)*N + (j0+jj);
      int4 e = ((const int4*)ei)[pidx];
      int spv = sp[pidx];
      int cnt = (e.x!=0)+(e.y!=0)+(e.z!=0)+(e.w!=0);
      float inv = 1.f/(float)(cnt>0?cnt:1);
      u16x8 t0a = *(const u16x8*)(Tb + (size_t)e.x*64);
      u16x8 t0b = *(const u16x8*)(Tb + (size_t)e.x*64 + 8);
      u16x8 t1a = *(const u16x8*)(Tb + (size_t)e.y*64 + 16);
      u16x8 t1b = *(const u16x8*)(Tb + (size_t)e.y*64 + 24);
      u16x8 t2a = *(const u16x8*)(Tb + (size_t)e.z*64 + 32);
      u16x8 t2b = *(const u16x8*)(Tb + (size_t)e.z*64 + 40);
      u16x8 t3a = *(const u16x8*)(Tb + (size_t)e.w*64 + 48);
      u16x8 t3b = *(const u16x8*)(Tb + (size_t)e.w*64 + 56);
      u16x8 sa  = *(const u16x8*)(seb + (size_t)spv*16);
      u16x8 sb  = *(const u16x8*)(seb + (size_t)spv*16 + 8);
      float v16[16];
      #pragma unroll
      for (int q2=0; q2<8; ++q2) {
        float ta = bf2fu(t0a[q2]) + bf2fu(t1a[q2]) + bf2fu(t2a[q2]) + bf2fu(t3a[q2]);
        v16[q2]   = ta*inv + bf2fu(sa[q2]);
        float tb = bf2fu(t0b[q2]) + bf2fu(t1b[q2]) + bf2fu(t2b[q2]) + bf2fu(t3b[q2]);
        v16[8+q2] = tb*inv + bf2fu(sb[q2]);
      }
      int Qj = (jj & 48) | ((jj & 3) << 2) | ((jj >> 2) & 3);
      int idxb = Qj*16 + (ii ^ ((Qj>>1)&15));
      #pragma unroll
      for (int hp=0; hp<8; ++hp) {
        unsigned lo = (unsigned)(unsigned short)f2bf(v16[2*hp]);
        unsigned hi = (unsigned)(unsigned short)f2bf(v16[2*hp+1]);
        bias_lds[hp*1024 + idxb] = (hi<<16) | lo;
      }
    }
    __syncthreads();
    // ---- phase B: per-wave, 2 heads ----
    #pragma unroll
    for (int hh=0; hh<2; ++hh) {
      int h = w*2 + hh;
      bf16x8 kf[4];
      #pragma unroll
      for (int mi=0; mi<4; ++mi)
        kf[mi] = *(const bf16x8*)(kb + (size_t)(j0+mi*16+lr)*HID + h*DH + kg*8);
      f32x4 s[4];
      #pragma unroll
      for (int mi=0; mi<4; ++mi)
        s[mi] = __builtin_amdgcn_mfma_f32_16x16x32_bf16(kf[mi], qf[hh], (f32x4){0,0,0,0}, 0, 0, 0);
      float pm = -INFINITY;
      #pragma unroll
      for (int mi=0; mi<4; ++mi) {
        #pragma unroll
        for (int r=0; r<4; ++r) {
          unsigned u = bias_lds[w*1024 + (mi*16 + r*4 + kg)*16
                                + (lr ^ ((mi*8 + r*2 + (kg>>1)) & 15))];
          float b = bf2fu((unsigned short)((h&1) ? (u>>16) : (u & 0xffff)));
          s[mi][r] += b;
          pm = fmaxf(pm, s[mi][r]);
        }
      }
      pm = fmaxf(pm, __shfl_xor(pm, 16));
      pm = fmaxf(pm, __shfl_xor(pm, 32));
      float newm = fmaxf(m[hh], pm);
      float fac = __expf(m[hh] - newm);
      float ev[4][4];
      float ts = 0.f;
      #pragma unroll
      for (int mi=0; mi<4; ++mi)
        #pragma unroll
        for (int r=0; r<4; ++r) { float e_ = __expf(s[mi][r] - newm); ev[mi][r] = e_; ts += e_; }
      ts += __shfl_xor(ts, 16);
      ts += __shfl_xor(ts, 32);
      lsum[hh] = lsum[hh]*fac + ts;
      m[hh] = newm;
      #pragma unroll
      for (int mi=0; mi<2; ++mi)
        #pragma unroll
        for (int r=0; r<4; ++r) accO[hh][mi][r] *= fac;
      unsigned u01[4][2];
      #pragma unroll
      for (int mi=0; mi<4; ++mi) {
        #pragma unroll
        for (int pr=0; pr<2; ++pr) {
          unsigned lo = (unsigned)(unsigned short)f2bf(ev[mi][2*pr]);
          unsigned hi = (unsigned)(unsigned short)f2bf(ev[mi][2*pr+1]);
          u01[mi][pr] = (hi<<16) | lo;
        }
      }
      #pragma unroll
      for (int ks=0; ks<2; ++ks) {
        unsigned Wd[4];
        #pragma unroll
        for (int wd=0; wd<4; ++wd) {
          int srcLane = lr + ((2*(kg&1) + (wd>>1)) << 4);
          int a = __shfl((int)u01[2*ks][wd&1],   srcLane);
          int b = __shfl((int)u01[2*ks+1][wd&1], srcLane);
          Wd[wd] = (kg>>1) ? (unsigned)b : (unsigned)a;
        }
        union { unsigned u[4]; bf16x8 v; } cvt;
        cvt.u[0]=Wd[0]; cvt.u[1]=Wd[1]; cvt.u[2]=Wd[2]; cvt.u[3]=Wd[3];
        bf16x8 pfrag = cvt.v;
        #pragma unroll
        for (int mi=0; mi<2; ++mi) {
          bf16x8 vf = *(const bf16x8*)(Vt + (size_t)(h*DH + mi*16 + lr)*N + j0 + ks*32 + kg*8);
          accO[hh][mi] = __builtin_amdgcn_mfma_f32_16x16x32_bf16(vf, pfrag, accO[hh][mi], 0, 0, 0);
        }
      }
    }
  }
  // ---- write partials ----
  #pragma unroll
  for (int hh=0; hh<2; ++hh) {
    int h = w*2 + hh;
    if (kg == 0) {
      Pm[(size_t)(jc*16+h)*N + i0 + lr] = m[hh];
      Pl[(size_t)(jc*16+h)*N + i0 + lr] = lsum[hh];
    }
    #pragma unroll
    for (int mi=0; mi<2; ++mi)
      #pragma unroll
      for (int r=0; r<4; ++r) {
        int d = mi*16 + kg*4 + r;
        Po[((size_t)(jc*16+h)*DH + d)*N + i0 + lr] = accO[hh][mi][r];
      }
  }
}

// ---------------- combine partials -> ob (bf16 [i][h*32+d]) ------------------
__global__ void attn_combine(const float* __restrict__ Pm, const float* __restrict__ Pl,
                             const float* __restrict__ Po, short* __restrict__ ob) {
  int bx = blockIdx.x;
  int h0 = (bx >> 4) * 4;
  int i0 = (bx & 15) * 64;
  int tid = threadIdx.x;
  int i = i0 + (tid & 63);
  int h = h0 + (tid >> 6);
  float mc[8];
  float M = -INFINITY;
  #pragma unroll
  for (int c=0; c<8; ++c) { mc[c] = Pm[(size_t)(c*16+h)*N + i]; M = fmaxf(M, mc[c]); }
  float wc[8]; float L = 0.f;
  #pragma unroll
  for (int c=0; c<8; ++c) { wc[c] = __expf(mc[c]-M); L += Pl[(size_t)(c*16+h)*N + i]*wc[c]; }
  float invL = 1.f / L;
  #pragma unroll
  for (int d0=0; d0<DH; d0+=4) {
    float o[4] = {0,0,0,0};
    #pragma unroll
    for (int c=0; c<8; ++c) {
      #pragma unroll
      for (int dd=0; dd<4; ++dd)
        o[dd] += wc[c] * Po[((size_t)(c*16+h)*DH + d0+dd)*N + i];
    }
    short4v st = { f2bf(o[0]*invL), f2bf(o[1]*invL), f2bf(o[2]*invL), f2bf(o[3]*invL) };
    *(short4v*)(ob + (size_t)i*HID + h*DH + d0) = st;
  }
}

// ---------------- residual + layernorm (+ optional bf16 copy) ----------------
__global__ void add_ln_k(const float* __restrict__ a, const float* __restrict__ b,
                         const float* __restrict__ g, const float* __restrict__ be,
                         float* __restrict__ out, short* __restrict__ outb) {
  int i = blockIdx.x; int tid = threadIdx.x;
  float4 av = ((const float4*)(a + (size_t)i*HID))[tid];
  float4 bv = ((const float4*)(b + (size_t)i*HID))[tid];
  float4 v;
  v.x = av.x+bv.x; v.y = av.y+bv.y; v.z = av.z+bv.z; v.w = av.w+bv.w;
  float s = v.x+v.y+v.z+v.w;
  float s2 = v.x*v.x+v.y*v.y+v.z*v.z+v.w*v.w;
  for (int o = 32; o; o >>= 1) { s += __shfl_xor(s, o); s2 += __shfl_xor(s2, o); }
  __shared__ float sa[2], sb[2];
  if ((tid & 63) == 0) { sa[tid>>6] = s; sb[tid>>6] = s2; }
  __syncthreads();
  s = sa[0]+sa[1]; s2 = sb[0]+sb[1];
  float mean = s*(1.f/HID);
  float var = s2*(1.f/HID) - mean*mean;
  float rinv = rsqrtf(var + 1e-5f);
  float4 gv = ((const float4*)g)[tid];
  float4 bev = ((const float4*)be)[tid];
  float4 r;
  r.x = (v.x-mean)*rinv*gv.x + bev.x;
  r.y = (v.y-mean)*rinv*gv.y + bev.y;
  r.z = (v.z-mean)*rinv*gv.z + bev.z;
  r.w = (v.w-mean)*rinv*gv.w + bev.w;
  ((float4*)(out + (size_t)i*HID))[tid] = r;
  if (outb) {
    short4v o = { f2bf(r.x), f2bf(r.y), f2bf(r.z), f2bf(r.w) };
    ((short4v*)(outb + (size_t)i*HID))[tid] = o;
  }
}

extern "C" void kernel_launch(void* const* d_in, const int* in_sizes, int n_in,
                              void* d_out, int out_size, void* d_ws, size_t ws_size,
                              hipStream_t stream) {
  const float* x            = (const float*)d_in[0];
  const int*   spatial_pos  = (const int*)d_in[1];
  const int*   edge_input   = (const int*)d_in[2];
  const int*   in_degree    = (const int*)d_in[3];
  const int*   out_degree   = (const int*)d_in[4];
  const float* spatial_emb  = (const float*)d_in[5];
  const float* edge_emb     = (const float*)d_in[6];
  const float* edge_pos_emb = (const float*)d_in[7];
  const float* in_deg_emb   = (const float*)d_in[8];
  const float* out_deg_emb  = (const float*)d_in[9];
  const float* Wq = (const float*)d_in[10]; const float* bq = (const float*)d_in[11];
  const float* Wk = (const float*)d_in[12]; const float* bk = (const float*)d_in[13];
  const float* Wv = (const float*)d_in[14]; const float* bv = (const float*)d_in[15];
  const float* Wo = (const float*)d_in[16]; const float* bo = (const float*)d_in[17];
  const float* W1 = (const float*)d_in[18]; const float* b1 = (const float*)d_in[19];
  const float* W2 = (const float*)d_in[20]; const float* b2 = (const float*)d_in[21];
  const float* g1 = (const float*)d_in[22]; const float* be1 = (const float*)d_in[23];
  const float* g2 = (const float*)d_in[24]; const float* be2 = (const float*)d_in[25];

  char* W = (char*)d_ws;
  short* Tb   = (short*)(W + 0);            // 131,200 B
  short* seb  = (short*)(W + 262144);       // 16 KB
  float* h    = (float*)(W + 524288);       // 2 MB
  float* y    = (float*)(W + 2621440);      // 2 MB
  float* h1   = (float*)(W + 4718592);      // 2 MB
  short* hb   = (short*)(W + 6815744);      // 1 MB
  short* qb   = (short*)(W + 7864320);      // 1 MB
  short* kb   = (short*)(W + 8912896);      // 1 MB
  short* Vt   = (short*)(W + 9961472);      // 1 MB
  short* ob   = (short*)(W + 11010048);     // 1 MB
  short* h1b  = (short*)(W + 12058624);     // 1 MB
  short* midb = (short*)(W + 13107200);     // 2 MB
  float* f2   = (float*)(W + 15204352);     // 2 MB
  short* Wtq  = (short*)(W + 17301504);     // 512 KB
  short* Wtk  = (short*)(W + 17825792);
  short* Wtv  = (short*)(W + 18350080);
  short* Wto  = (short*)(W + 18874368);
  short* Wt1  = (short*)(W + 19398656);     // 1 MB
  short* Wt2  = (short*)(W + 20447232);     // 1 MB
  float* Pm   = (float*)(W + 21495808);     // 512 KB
  float* Pl   = (float*)(W + 22020096);     // 512 KB
  float* Po   = (float*)(W + 22544384);     // 16 MB -> ends 39,321,600
  float* out  = (float*)d_out;

  centrality_k<<<N, 128, 0, stream>>>(x, in_degree, out_degree, in_deg_emb, out_deg_emb, h, hb);
  prep_tables<<<257, 256, 0, stream>>>(edge_emb, edge_pos_emb, spatial_emb, Tb, seb);

  wtr4_k<<<dim3(16,16,4), 256, 0, stream>>>(Wq, Wk, Wv, Wo, Wtq, Wtk, Wtv, Wto);
  wtr_k<<<dim3(32,16), 256, 0, stream>>>(W1, Wt1, 512, 1024);
  wtr_k<<<dim3(16,32), 256, 0, stream>>>(W2, Wt2, 1024, 512);

  qkv_gemm<<<dim3(16,16,3), 256, 0, stream>>>(hb, Wtq, Wtk, Wtv, bq, bk, bv, qb, kb, Vt);

  fused_attn<<<dim3(8,64), 512, 0, stream>>>(qb, kb, Vt, spatial_pos, edge_input, seb, Tb,
                                             Pm, Pl, Po);
  attn_combine<<<64, 256, 0, stream>>>(Pm, Pl, Po, ob);

  gemm_mfma<32,0,0><<<dim3(16,16), 256, 0, stream>>>(ob, Wto, bo, 1.f, y, nullptr, 512, 512);
  add_ln_k<<<N, 128, 0, stream>>>(h, y, g1, be1, h1, h1b);
  gemm_mfma<64,1,1><<<dim3(16,16), 256, 0, stream>>>(h1b, Wt1, b1, 1.f, nullptr, midb, 512, 1024);
  gemm_mfma<32,0,0><<<dim3(16,16), 256, 0, stream>>>(midb, Wt2, b2, 1.f, f2, nullptr, 1024, 512);
  add_ln_k<<<N, 128, 0, stream>>>(h1, f2, g2, be2, out, nullptr);
}

// Round 6
// 94.600 us; speedup vs baseline: 5.0445x; 1.2301x over previous
//
#include <hip/hip_runtime.h>
#include <math.h>

#define N 1024
#define HID 512
#define NH 16
#define DH 32
#define NEDGE 1025

typedef __attribute__((ext_vector_type(8))) __bf16 bf16x8;
typedef __attribute__((ext_vector_type(4))) short short4v;
typedef __attribute__((ext_vector_type(4))) float f32x4;

__device__ inline short f2bf(float f) {
  unsigned u = __builtin_bit_cast(unsigned, f);
  u += 0x7fffu + ((u >> 16) & 1u);
  return (short)(u >> 16);
}
__device__ inline float h2f(unsigned short hs) {
  return (float)__builtin_bit_cast(_Float16, hs);
}
// OCP e4m3fn encode (RNE for normals)
__device__ inline unsigned char f2e4m3(float f) {
  unsigned u = __builtin_bit_cast(unsigned, f);
  unsigned s = (u >> 24) & 0x80;
  float a = fabsf(f);
  if (a >= 448.f) return (unsigned char)(s | 0x7e);
  if (a < 0.015625f) {                       // denormal: k × 2^-9
    int k = (int)(a * 512.f + 0.5f);
    if (k >= 8) return (unsigned char)(s | 0x08);
    return (unsigned char)(s | k);
  }
  int e = ((u >> 23) & 0xff) - 127;
  unsigned m = (u >> 20) & 7;
  unsigned rest = u & 0xfffff;
  if (rest > 0x80000 || (rest == 0x80000 && (m & 1))) {
    m += 1;
    if (m == 8) { m = 0; e += 1; if (e > 8) return (unsigned char)(s | 0x7e); }
  }
  return (unsigned char)(s | ((unsigned)(e + 7) << 3) | m);
}

// ---------------- centrality: h = x + ide[ind] + ode[outd]; also bf16 copy ---
__global__ void centrality_k(const float* __restrict__ x, const int* __restrict__ ind,
                             const int* __restrict__ outd, const float* __restrict__ ide,
                             const float* __restrict__ ode, float* __restrict__ h,
                             short* __restrict__ hb) {
  int i = blockIdx.x; int t = threadIdx.x;
  int a = ind[i], b = outd[i];
  float4 xv = ((const float4*)(x + (size_t)i*HID))[t];
  float4 av = ((const float4*)(ide + (size_t)a*HID))[t];
  float4 bv = ((const float4*)(ode + (size_t)b*HID))[t];
  float4 r;
  r.x = xv.x+av.x+bv.x; r.y = xv.y+av.y+bv.y;
  r.z = xv.z+av.z+bv.z; r.w = xv.w+av.w+bv.w;
  ((float4*)(h + (size_t)i*HID))[t] = r;
  short4v o = { f2bf(r.x), f2bf(r.y), f2bf(r.z), f2bf(r.w) };
  ((short4v*)(hb + (size_t)i*HID))[t] = o;
}

// ---------------- tables: Tb8[e][k][h]=e4m3(64*sum_d ee*pw); seb8=e4m3(se) ---
__global__ void prep_tables(const float* __restrict__ ee, const float* __restrict__ epe,
                            const float* __restrict__ se,
                            unsigned char* __restrict__ Tb8, unsigned char* __restrict__ seb8) {
  int t = blockIdx.x*256 + threadIdx.x;
  if (t < NEDGE*64) {
    int e = t >> 6; int r = t & 63; int k = r >> 4; int hh = r & 15;
    const float* erow = ee + (size_t)e*32;
    const float* w = epe + k*512 + hh;
    float acc = 0.f;
    #pragma unroll
    for (int d = 0; d < 32; ++d) acc += erow[d] * w[d*16];
    Tb8[t] = f2e4m3(acc * 64.f);
  }
  if (t < 512*16) seb8[t] = f2e4m3(se[t]);
}

// ---------------- weight transpose + bf16: Wt[n][k] = bf16(Win[k][n]) --------
__device__ inline void wtr_body(const float* __restrict__ Win, short* __restrict__ Wt,
                                int K, int Nc) {
  __shared__ float tile[32][33];
  int n0 = blockIdx.x*32, k0 = blockIdx.y*32;
  int tid = threadIdx.x;
  int r = tid >> 3, c = (tid & 7) * 4;
  float4 v = *(const float4*)(Win + (size_t)(k0+r)*Nc + n0 + c);
  tile[r][c]=v.x; tile[r][c+1]=v.y; tile[r][c+2]=v.z; tile[r][c+3]=v.w;
  __syncthreads();
  short4v o = { f2bf(tile[c+0][r]), f2bf(tile[c+1][r]), f2bf(tile[c+2][r]), f2bf(tile[c+3][r]) };
  *(short4v*)(Wt + (size_t)(n0+r)*K + k0 + c) = o;
}
__global__ void wtr_k(const float* __restrict__ Win, short* __restrict__ Wt, int K, int Nc) {
  wtr_body(Win, Wt, K, Nc);
}
__global__ void wtr4_k(const float* __restrict__ W0, const float* __restrict__ W1_,
                       const float* __restrict__ W2_, const float* __restrict__ W3,
                       short* __restrict__ T0, short* __restrict__ T1,
                       short* __restrict__ T2, short* __restrict__ T3) {
  int z = blockIdx.z;
  const float* Win = z==0 ? W0 : z==1 ? W1_ : z==2 ? W2_ : W3;
  short* Wt = z==0 ? T0 : z==1 ? T1 : z==2 ? T2 : T3;
  wtr_body(Win, Wt, 512, 512);
}

// ---------------- MFMA GEMM: C[M][Nc] = A[M][K](bf16) @ Bt[Nc][K]^T + bias ---
template<int BN, int RELU, int OUT>
__launch_bounds__(256)
__global__ void gemm_mfma(const short* __restrict__ A, const short* __restrict__ Bt,
                          const float* __restrict__ bias, float scale,
                          float* __restrict__ Cf, short* __restrict__ Cb,
                          int K, int Nc) {
  __shared__ short As[64*64];
  __shared__ short Bs[BN*64];
  constexpr int WN = BN/32;
  constexpr int WM = 4/WN;
  constexpr int MI = 64/(WM*16);
  int tid = threadIdx.x;
  int w = tid >> 6, l = tid & 63;
  int lr = l & 15, kg = l >> 4;
  int wn = (WN == 1) ? 0 : (w & 1);
  int wm = (WN == 1) ? w : (w >> 1);
  int i0 = blockIdx.y*64, n0 = blockIdx.x*BN;
  int srow = tid >> 3, sslot = tid & 7;
  f32x4 acc[MI][2];
  #pragma unroll
  for (int mi=0; mi<MI; ++mi)
    #pragma unroll
    for (int ni=0; ni<2; ++ni) acc[mi][ni] = (f32x4){0.f,0.f,0.f,0.f};
  const short* Ag = A + (size_t)i0*K;
  const short* Bg = Bt + (size_t)n0*K;
  for (int k0 = 0; k0 < K; k0 += 64) {
    bf16x8 va0 = *(const bf16x8*)(Ag + (size_t)srow*K + k0 + sslot*8);
    bf16x8 va1 = *(const bf16x8*)(Ag + (size_t)(srow+32)*K + k0 + sslot*8);
    bf16x8 vb0 = *(const bf16x8*)(Bg + (size_t)srow*K + k0 + sslot*8);
    bf16x8 vb1;
    if (BN == 64) vb1 = *(const bf16x8*)(Bg + (size_t)(srow+32)*K + k0 + sslot*8);
    __syncthreads();
    *(bf16x8*)((char*)As + srow*128 + ((sslot ^ (srow&7))<<4)) = va0;
    *(bf16x8*)((char*)As + (srow+32)*128 + ((sslot ^ (srow&7))<<4)) = va1;
    *(bf16x8*)((char*)Bs + srow*128 + ((sslot ^ (srow&7))<<4)) = vb0;
    if (BN == 64)
      *(bf16x8*)((char*)Bs + (srow+32)*128 + ((sslot ^ (srow&7))<<4)) = vb1;
    __syncthreads();
    #pragma unroll
    for (int ks = 0; ks < 2; ++ks) {
      bf16x8 fa[MI], fb[2];
      #pragma unroll
      for (int mi=0; mi<MI; ++mi) {
        int r = wm*(64/WM) + mi*16 + lr;
        fa[mi] = *(const bf16x8*)((const char*)As + r*128 + (((ks*4+kg) ^ (r&7))<<4));
      }
      #pragma unroll
      for (int ni=0; ni<2; ++ni) {
        int r = wn*32 + ni*16 + lr;
        fb[ni] = *(const bf16x8*)((const char*)Bs + r*128 + (((ks*4+kg) ^ (r&7))<<4));
      }
      #pragma unroll
      for (int mi=0; mi<MI; ++mi)
        #pragma unroll
        for (int ni=0; ni<2; ++ni)
          acc[mi][ni] = __builtin_amdgcn_mfma_f32_16x16x32_bf16(fa[mi], fb[ni], acc[mi][ni], 0, 0, 0);
    }
  }
  #pragma unroll
  for (int mi=0; mi<MI; ++mi) {
    #pragma unroll
    for (int ni=0; ni<2; ++ni) {
      int c = n0 + wn*32 + ni*16 + lr;
      float bb = bias[c];
      float vv[4];
      #pragma unroll
      for (int r=0; r<4; ++r) {
        float v = (acc[mi][ni][r] + bb) * scale;
        if (RELU) v = fmaxf(v, 0.f);
        vv[r] = v;
      }
      int rr0 = i0 + wm*(64/WM) + mi*16 + kg*4;
      if (OUT == 0) {
        #pragma unroll
        for (int r=0; r<4; ++r) Cf[(size_t)(rr0+r)*Nc + c] = vv[r];
      } else {
        #pragma unroll
        for (int r=0; r<4; ++r) Cb[(size_t)(rr0+r)*Nc + c] = f2bf(vv[r]);
      }
    }
  }
}

// ---------------- batched Q/K/V GEMM (BN=32, K=Nc=512) ----------------------
__launch_bounds__(256)
__global__ void qkv_gemm(const short* __restrict__ A,
                         const short* __restrict__ Wtq, const short* __restrict__ Wtk,
                         const short* __restrict__ Wtv,
                         const float* __restrict__ bq, const float* __restrict__ bk,
                         const float* __restrict__ bv,
                         short* __restrict__ qb, short* __restrict__ kb,
                         short* __restrict__ Vt) {
  __shared__ short As[64*64];
  __shared__ short Bs[32*64];
  int z = blockIdx.z;
  const short* Bt = z==0 ? Wtq : z==1 ? Wtk : Wtv;
  const float* bias = z==0 ? bq : z==1 ? bk : bv;
  const float scale = z==0 ? 5.65685424949238019521f : 1.f;
  int tid = threadIdx.x;
  int w = tid >> 6, l = tid & 63, lr = l & 15, kg = l >> 4;
  int i0 = blockIdx.y*64, n0 = blockIdx.x*32;
  int srow = tid >> 3, sslot = tid & 7;
  f32x4 acc[2] = {(f32x4){0,0,0,0},(f32x4){0,0,0,0}};
  const short* Ag = A + (size_t)i0*512;
  const short* Bg = Bt + (size_t)n0*512;
  for (int k0 = 0; k0 < 512; k0 += 64) {
    bf16x8 va0 = *(const bf16x8*)(Ag + (size_t)srow*512 + k0 + sslot*8);
    bf16x8 va1 = *(const bf16x8*)(Ag + (size_t)(srow+32)*512 + k0 + sslot*8);
    bf16x8 vb0 = *(const bf16x8*)(Bg + (size_t)srow*512 + k0 + sslot*8);
    __syncthreads();
    *(bf16x8*)((char*)As + srow*128 + ((sslot ^ (srow&7))<<4)) = va0;
    *(bf16x8*)((char*)As + (srow+32)*128 + ((sslot ^ (srow&7))<<4)) = va1;
    *(bf16x8*)((char*)Bs + srow*128 + ((sslot ^ (srow&7))<<4)) = vb0;
    __syncthreads();
    #pragma unroll
    for (int ks = 0; ks < 2; ++ks) {
      int ra = w*16 + lr;
      bf16x8 fa = *(const bf16x8*)((const char*)As + ra*128 + (((ks*4+kg) ^ (ra&7))<<4));
      #pragma unroll
      for (int ni=0; ni<2; ++ni) {
        int rb = ni*16 + lr;
        bf16x8 fb = *(const bf16x8*)((const char*)Bs + rb*128 + (((ks*4+kg) ^ (rb&7))<<4));
        acc[ni] = __builtin_amdgcn_mfma_f32_16x16x32_bf16(fa, fb, acc[ni], 0, 0, 0);
      }
    }
  }
  short* Cb = z==0 ? qb : kb;
  #pragma unroll
  for (int ni=0; ni<2; ++ni) {
    int c = n0 + ni*16 + lr;
    float bb = bias[c];
    float vv[4];
    #pragma unroll
    for (int r=0; r<4; ++r) vv[r] = (acc[ni][r] + bb) * scale;
    int rr0 = i0 + w*16 + kg*4;
    if (z < 2) {
      #pragma unroll
      for (int r=0; r<4; ++r) Cb[(size_t)(rr0+r)*512 + c] = f2bf(vv[r]);
    } else {
      short4v o = { f2bf(vv[0]), f2bf(vv[1]), f2bf(vv[2]), f2bf(vv[3]) };
      *(short4v*)(Vt + (size_t)c*N + rr0) = o;   // Vt[c][row]
    }
  }
}

// ---------------- fused flash attention with Graphormer bias -----------------
// grid (16 j-chunks of 64, 64 i-tiles), 512 threads; wave w = heads 2w,2w+1.
__launch_bounds__(512, 6)
__global__ void fused_attn(const short* __restrict__ qb, const short* __restrict__ kb,
                           const short* __restrict__ Vt, const int* __restrict__ sp,
                           const int* __restrict__ ei,
                           const unsigned char* __restrict__ seb8,
                           const unsigned char* __restrict__ Tb8,
                           float* __restrict__ Pm, float* __restrict__ Pl,
                           float* __restrict__ Po) {
  __shared__ unsigned bias_lds[8*1024];   // [hp][ Q(j)*16 + (i ^ ((Q(j)>>1)&15)) ] f16 pairs
  int tid = threadIdx.x;
  int w = tid >> 6, l = tid & 63, lr = l & 15, kg = l >> 4;
  int i0 = blockIdx.y*16;
  int jc = blockIdx.x;
  int j0 = jc*64;
  bf16x8 qf[2];
  #pragma unroll
  for (int hh=0; hh<2; ++hh)
    qf[hh] = *(const bf16x8*)(qb + (size_t)(i0+lr)*HID + (w*2+hh)*DH + kg*8);

  // ---- phase A: cooperative bias tile, j-fast (coalesced ei/sp) ----
  #pragma unroll
  for (int pp=0; pp<2; ++pp) {
    int p = pp*512 + tid;               // 0..1023
    int jj = p & 63, ii = p >> 6;
    size_t pidx = (size_t)(i0+ii)*N + (j0+jj);
    int4 e = ((const int4*)ei)[pidx];
    int spv = sp[pidx];
    int cnt = (e.x!=0)+(e.y!=0)+(e.z!=0)+(e.w!=0);
    float inv64 = 0.015625f/(float)(cnt>0?cnt:1);
    int4 r0 = *(const int4*)(Tb8 + (size_t)e.x*64);
    int4 r1 = *(const int4*)(Tb8 + (size_t)e.y*64 + 16);
    int4 r2 = *(const int4*)(Tb8 + (size_t)e.z*64 + 32);
    int4 r3 = *(const int4*)(Tb8 + (size_t)e.w*64 + 48);
    int4 sv = *(const int4*)(seb8 + (size_t)spv*16);
    int Qj = (jj & 48) | ((jj & 3) << 2) | ((jj >> 2) & 3);
    int idxb = Qj*16 + (ii ^ ((Qj>>1)&15));
    int rq[4] = { r0.x, r0.y, r0.z, r0.w };
    int r1q[4] = { r1.x, r1.y, r1.z, r1.w };
    int r2q[4] = { r2.x, r2.y, r2.z, r2.w };
    int r3q[4] = { r3.x, r3.y, r3.z, r3.w };
    int svq[4] = { sv.x, sv.y, sv.z, sv.w };
    #pragma unroll
    for (int q = 0; q < 4; ++q) {
      #define BIAS_WS(WS)                                                        \
      {                                                                          \
        auto a0 = __builtin_amdgcn_cvt_pk_f32_fp8(rq[q],  WS);                   \
        auto a1 = __builtin_amdgcn_cvt_pk_f32_fp8(r1q[q], WS);                   \
        auto a2 = __builtin_amdgcn_cvt_pk_f32_fp8(r2q[q], WS);                   \
        auto a3 = __builtin_amdgcn_cvt_pk_f32_fp8(r3q[q], WS);                   \
        auto ss = __builtin_amdgcn_cvt_pk_f32_fp8(svq[q], WS);                   \
        float tx = (a0[0]+a1[0]) + (a2[0]+a3[0]);                                \
        float ty = (a0[1]+a1[1]) + (a2[1]+a3[1]);                                \
        float bx = fmaf(tx, inv64, ss[0]);                                       \
        float by = fmaf(ty, inv64, ss[1]);                                       \
        auto pk = __builtin_amdgcn_cvt_pkrtz(bx, by);                            \
        bias_lds[(q*2+WS)*1024 + idxb] = __builtin_bit_cast(unsigned, pk);       \
      }
      BIAS_WS(0)
      BIAS_WS(1)
      #undef BIAS_WS
    }
  }
  __syncthreads();

  // ---- phase B: per-wave, 2 heads ----
  float m[2], lsum[2];
  f32x4 accO[2][2];
  #pragma unroll
  for (int hh=0; hh<2; ++hh) {
    int h = w*2 + hh;
    bf16x8 kf[4];
    #pragma unroll
    for (int mi=0; mi<4; ++mi)
      kf[mi] = *(const bf16x8*)(kb + (size_t)(j0+mi*16+lr)*HID + h*DH + kg*8);
    f32x4 s[4];
    #pragma unroll
    for (int mi=0; mi<4; ++mi)
      s[mi] = __builtin_amdgcn_mfma_f32_16x16x32_bf16(kf[mi], qf[hh], (f32x4){0,0,0,0}, 0, 0, 0);
    float pm = -INFINITY;
    #pragma unroll
    for (int mi=0; mi<4; ++mi) {
      #pragma unroll
      for (int r=0; r<4; ++r) {
        unsigned u = bias_lds[w*1024 + (mi*16 + r*4 + kg)*16
                              + (lr ^ ((mi*8 + r*2 + (kg>>1)) & 15))];
        float b = h2f((unsigned short)((h&1) ? (u>>16) : (u & 0xffff)));
        s[mi][r] += b;
        pm = fmaxf(pm, s[mi][r]);
      }
    }
    pm = fmaxf(pm, __shfl_xor(pm, 16));
    pm = fmaxf(pm, __shfl_xor(pm, 32));
    m[hh] = pm;
    float ev[4][4];
    float ts = 0.f;
    #pragma unroll
    for (int mi=0; mi<4; ++mi)
      #pragma unroll
      for (int r=0; r<4; ++r) { float e_ = __expf(s[mi][r] - pm); ev[mi][r] = e_; ts += e_; }
    ts += __shfl_xor(ts, 16);
    ts += __shfl_xor(ts, 32);
    lsum[hh] = ts;
    accO[hh][0] = (f32x4){0,0,0,0};
    accO[hh][1] = (f32x4){0,0,0,0};
    unsigned u01[4][2];
    #pragma unroll
    for (int mi=0; mi<4; ++mi) {
      #pragma unroll
      for (int pr=0; pr<2; ++pr) {
        unsigned lo = (unsigned)(unsigned short)f2bf(ev[mi][2*pr]);
        unsigned hi = (unsigned)(unsigned short)f2bf(ev[mi][2*pr+1]);
        u01[mi][pr] = (hi<<16) | lo;
      }
    }
    #pragma unroll
    for (int ks=0; ks<2; ++ks) {
      unsigned Wd[4];
      #pragma unroll
      for (int wd=0; wd<4; ++wd) {
        int srcLane = lr + ((2*(kg&1) + (wd>>1)) << 4);
        int a = __shfl((int)u01[2*ks][wd&1],   srcLane);
        int b = __shfl((int)u01[2*ks+1][wd&1], srcLane);
        Wd[wd] = (kg>>1) ? (unsigned)b : (unsigned)a;
      }
      union { unsigned u[4]; bf16x8 v; } cvt;
      cvt.u[0]=Wd[0]; cvt.u[1]=Wd[1]; cvt.u[2]=Wd[2]; cvt.u[3]=Wd[3];
      bf16x8 pfrag = cvt.v;
      #pragma unroll
      for (int mi=0; mi<2; ++mi) {
        bf16x8 vf = *(const bf16x8*)(Vt + (size_t)(h*DH + mi*16 + lr)*N + j0 + ks*32 + kg*8);
        accO[hh][mi] = __builtin_amdgcn_mfma_f32_16x16x32_bf16(vf, pfrag, accO[hh][mi], 0, 0, 0);
      }
    }
  }
  // ---- write partials ----
  #pragma unroll
  for (int hh=0; hh<2; ++hh) {
    int h = w*2 + hh;
    if (kg == 0) {
      Pm[(size_t)(jc*16+h)*N + i0 + lr] = m[hh];
      Pl[(size_t)(jc*16+h)*N + i0 + lr] = lsum[hh];
    }
    #pragma unroll
    for (int mi=0; mi<2; ++mi)
      #pragma unroll
      for (int r=0; r<4; ++r) {
        int d = mi*16 + kg*4 + r;
        Po[((size_t)(jc*16+h)*DH + d)*N + i0 + lr] = accO[hh][mi][r];
      }
  }
}

// ---------------- combine partials -> ob (bf16 [i][h*32+d]) ------------------
__global__ void attn_combine(const float* __restrict__ Pm, const float* __restrict__ Pl,
                             const float* __restrict__ Po, short* __restrict__ ob) {
  int h = blockIdx.y;
  int i = blockIdx.x*64 + (threadIdx.x & 63);
  int dq = threadIdx.x >> 6;                 // 0..3 (8 d's each)
  float mcs[16];
  float M = -INFINITY;
  #pragma unroll
  for (int c=0; c<16; ++c) { mcs[c] = Pm[(size_t)(c*16+h)*N + i]; M = fmaxf(M, mcs[c]); }
  float wc[16]; float L = 0.f;
  #pragma unroll
  for (int c=0; c<16; ++c) { wc[c] = __expf(mcs[c]-M); L += Pl[(size_t)(c*16+h)*N + i]*wc[c]; }
  float invL = 1.f / L;
  float o[8] = {0,0,0,0,0,0,0,0};
  #pragma unroll
  for (int c=0; c<16; ++c) {
    #pragma unroll
    for (int dd=0; dd<8; ++dd)
      o[dd] += wc[c] * Po[((size_t)(c*16+h)*DH + dq*8+dd)*N + i];
  }
  short4v s0 = { f2bf(o[0]*invL), f2bf(o[1]*invL), f2bf(o[2]*invL), f2bf(o[3]*invL) };
  short4v s1 = { f2bf(o[4]*invL), f2bf(o[5]*invL), f2bf(o[6]*invL), f2bf(o[7]*invL) };
  *(short4v*)(ob + (size_t)i*HID + h*DH + dq*8) = s0;
  *(short4v*)(ob + (size_t)i*HID + h*DH + dq*8 + 4) = s1;
}

// ---------------- residual + layernorm (+ optional bf16 copy) ----------------
__global__ void add_ln_k(const float* __restrict__ a, const float* __restrict__ b,
                         const float* __restrict__ g, const float* __restrict__ be,
                         float* __restrict__ out, short* __restrict__ outb) {
  int i = blockIdx.x; int tid = threadIdx.x;
  float4 av = ((const float4*)(a + (size_t)i*HID))[tid];
  float4 bv = ((const float4*)(b + (size_t)i*HID))[tid];
  float4 v;
  v.x = av.x+bv.x; v.y = av.y+bv.y; v.z = av.z+bv.z; v.w = av.w+bv.w;
  float s = v.x+v.y+v.z+v.w;
  float s2 = v.x*v.x+v.y*v.y+v.z*v.z+v.w*v.w;
  for (int o = 32; o; o >>= 1) { s += __shfl_xor(s, o); s2 += __shfl_xor(s2, o); }
  __shared__ float sa[2], sb[2];
  if ((tid & 63) == 0) { sa[tid>>6] = s; sb[tid>>6] = s2; }
  __syncthreads();
  s = sa[0]+sa[1]; s2 = sb[0]+sb[1];
  float mean = s*(1.f/HID);
  float var = s2*(1.f/HID) - mean*mean;
  float rinv = rsqrtf(var + 1e-5f);
  float4 gv = ((const float4*)g)[tid];
  float4 bev = ((const float4*)be)[tid];
  float4 r;
  r.x = (v.x-mean)*rinv*gv.x + bev.x;
  r.y = (v.y-mean)*rinv*gv.y + bev.y;
  r.z = (v.z-mean)*rinv*gv.z + bev.z;
  r.w = (v.w-mean)*rinv*gv.w + bev.w;
  ((float4*)(out + (size_t)i*HID))[tid] = r;
  if (outb) {
    short4v o = { f2bf(r.x), f2bf(r.y), f2bf(r.z), f2bf(r.w) };
    ((short4v*)(outb + (size_t)i*HID))[tid] = o;
  }
}

extern "C" void kernel_launch(void* const* d_in, const int* in_sizes, int n_in,
                              void* d_out, int out_size, void* d_ws, size_t ws_size,
                              hipStream_t stream) {
  const float* x            = (const float*)d_in[0];
  const int*   spatial_pos  = (const int*)d_in[1];
  const int*   edge_input   = (const int*)d_in[2];
  const int*   in_degree    = (const int*)d_in[3];
  const int*   out_degree   = (const int*)d_in[4];
  const float* spatial_emb  = (const float*)d_in[5];
  const float* edge_emb     = (const float*)d_in[6];
  const float* edge_pos_emb = (const float*)d_in[7];
  const float* in_deg_emb   = (const float*)d_in[8];
  const float* out_deg_emb  = (const float*)d_in[9];
  const float* Wq = (const float*)d_in[10]; const float* bq = (const float*)d_in[11];
  const float* Wk = (const float*)d_in[12]; const float* bk = (const float*)d_in[13];
  const float* Wv = (const float*)d_in[14]; const float* bv = (const float*)d_in[15];
  const float* Wo = (const float*)d_in[16]; const float* bo = (const float*)d_in[17];
  const float* W1 = (const float*)d_in[18]; const float* b1 = (const float*)d_in[19];
  const float* W2 = (const float*)d_in[20]; const float* b2 = (const float*)d_in[21];
  const float* g1 = (const float*)d_in[22]; const float* be1 = (const float*)d_in[23];
  const float* g2 = (const float*)d_in[24]; const float* be2 = (const float*)d_in[25];

  char* W = (char*)d_ws;
  unsigned char* Tb8  = (unsigned char*)(W + 0);        // 65,600 B
  unsigned char* seb8 = (unsigned char*)(W + 131072);   // 8,192 B
  float* h    = (float*)(W + 262144);       // 2 MB
  float* y    = (float*)(W + 2359296);      // 2 MB
  float* h1   = (float*)(W + 4456448);      // 2 MB
  short* hb   = (short*)(W + 6553600);      // 1 MB
  short* qb   = (short*)(W + 7602176);      // 1 MB
  short* kb   = (short*)(W + 8650752);      // 1 MB
  short* Vt   = (short*)(W + 9699328);      // 1 MB
  short* ob   = (short*)(W + 10747904);     // 1 MB
  short* h1b  = (short*)(W + 11796480);     // 1 MB
  short* midb = (short*)(W + 12845056);     // 2 MB
  float* f2   = (float*)(W + 14942208);     // 2 MB
  short* Wtq  = (short*)(W + 17039360);     // 512 KB
  short* Wtk  = (short*)(W + 17563648);
  short* Wtv  = (short*)(W + 18087936);
  short* Wto  = (short*)(W + 18612224);
  short* Wt1  = (short*)(W + 19136512);     // 1 MB
  short* Wt2  = (short*)(W + 20185088);     // 1 MB
  float* Pm   = (float*)(W + 21233664);     // 1 MB
  float* Pl   = (float*)(W + 22282240);     // 1 MB
  float* Po   = (float*)(W + 23330816);     // 32 MB -> ends 56,885,248
  float* out  = (float*)d_out;

  centrality_k<<<N, 128, 0, stream>>>(x, in_degree, out_degree, in_deg_emb, out_deg_emb, h, hb);
  prep_tables<<<257, 256, 0, stream>>>(edge_emb, edge_pos_emb, spatial_emb, Tb8, seb8);

  wtr4_k<<<dim3(16,16,4), 256, 0, stream>>>(Wq, Wk, Wv, Wo, Wtq, Wtk, Wtv, Wto);
  wtr_k<<<dim3(32,16), 256, 0, stream>>>(W1, Wt1, 512, 1024);
  wtr_k<<<dim3(16,32), 256, 0, stream>>>(W2, Wt2, 1024, 512);

  qkv_gemm<<<dim3(16,16,3), 256, 0, stream>>>(hb, Wtq, Wtk, Wtv, bq, bk, bv, qb, kb, Vt);

  fused_attn<<<dim3(16,64), 512, 0, stream>>>(qb, kb, Vt, spatial_pos, edge_input, seb8, Tb8,
                                              Pm, Pl, Po);
  attn_combine<<<dim3(16,16), 256, 0, stream>>>(Pm, Pl, Po, ob);

  gemm_mfma<32,0,0><<<dim3(16,16), 256, 0, stream>>>(ob, Wto, bo, 1.f, y, nullptr, 512, 512);
  add_ln_k<<<N, 128, 0, stream>>>(h, y, g1, be1, h1, h1b);
  gemm_mfma<64,1,1><<<dim3(16,16), 256, 0, stream>>>(h1b, Wt1, b1, 1.f, nullptr, midb, 512, 1024);
  gemm_mfma<32,0,0><<<dim3(16,16), 256, 0, stream>>>(midb, Wt2, b2, 1.f, f2, nullptr, 1024, 512);
  add_ln_k<<<N, 128, 0, stream>>>(h1, f2, g2, be2, out, nullptr);
}